// Round 17
// baseline (459.645 us; speedup 1.0000x reference)
//
#include <hip/hip_runtime.h>
#include <hip/hip_bf16.h>
#include <hip/hip_cooperative_groups.h>

namespace cg = cooperative_groups;

#define D 64
#define BSH 6            // log2(nodes per bucket)
#define BNODES 64
#define NBMAX 2048       // LDS hist capacity (N <= 131072)
#define EB 4096          // edges per hist/fill block

typedef _Float16 f16;
typedef _Float16 f16x4 __attribute__((ext_vector_type(4)));
typedef _Float16 f16x8 __attribute__((ext_vector_type(8)));
typedef float f32x4 __attribute__((ext_vector_type(4)));

__device__ __forceinline__ int sw6(int m, int k) {  // row stride 64 f16
    return (m << 6) + ((((k >> 3) ^ (m & 7)) & 7) << 3) + (k & 7);
}

// ---------------------------------------------------------------------------
// FUSED preprocessing (r17): hist + scan + fill in ONE cooperative kernel.
// 391 co-resident blocks keep dv[] in regs and lhist in LDS across two
// grid.sync()s — saves 2 launches + a full 6.4MB dst re-read + re-histogram.
// ---------------------------------------------------------------------------
__global__ __launch_bounds__(256) void bucket_prep(
    const int* __restrict__ dst, const int* __restrict__ src,
    int* __restrict__ bhist, int* __restrict__ boff,
    int* __restrict__ bcursor, int2* __restrict__ eixA, int E, int NB)
{
    cg::grid_group grid = cg::this_grid();
    __shared__ int lhist[NBMAX];
    __shared__ int lcur[NBMAX];
    __shared__ int sscan[256];

    int tid = threadIdx.x;
    for (int b = tid; b < NB; b += 256) lhist[b] = 0;
    __syncthreads();

    // ---- P1: local histogram over this block's EB chunk ----
    int base = blockIdx.x * EB;
    int dv[EB / 256];
#pragma unroll
    for (int r = 0; r < EB / 256; ++r) {
        int e = base + r * 256 + tid;
        dv[r] = (e < E) ? dst[e] : -1;
        if (dv[r] >= 0) atomicAdd(&lhist[dv[r] >> BSH], 1);
    }
    __syncthreads();
    for (int b = tid; b < NB; b += 256) {
        int v = lhist[b];
        if (v) atomicAdd(&bhist[b], v);
    }
    grid.sync();

    // ---- P2: exclusive scan of bhist (block 0 only) ----
    if (blockIdx.x == 0) {
        int chunk = (NB + 255) / 256;
        int b0 = tid * chunk;
        int b1 = min(b0 + chunk, NB);
        int s = 0;
        for (int b = b0; b < b1; ++b) s += bhist[b];
        sscan[tid] = s;
        __syncthreads();
        for (int d2 = 1; d2 < 256; d2 <<= 1) {
            int v = (tid >= d2) ? sscan[tid - d2] : 0;
            __syncthreads();
            sscan[tid] += v;
            __syncthreads();
        }
        int run = (tid == 0) ? 0 : sscan[tid - 1];
        for (int b = b0; b < b1; ++b) {
            boff[b] = run;
            bcursor[b] = run;
            run += bhist[b];
        }
        if (tid == 255) boff[NB] = sscan[255];
    }
    grid.sync();

    // ---- P3: fill using saved dv + lhist (only src re-read needed) ----
    for (int b = tid; b < NB; b += 256) {
        int v = lhist[b];
        lcur[b] = v ? atomicAdd(&bcursor[b], v) : 0;
    }
    __syncthreads();
#pragma unroll
    for (int r = 0; r < EB / 256; ++r) {
        int e = base + r * 256 + tid;
        if (dv[r] >= 0) {
            int p = atomicAdd(&lcur[dv[r] >> BSH], 1);
            eixA[p] = make_int2(src[e], dv[r]);
        }
    }
}

// ---------------------------------------------------------------------------
// Per-bucket exact counting sort (64 bins in LDS) -> globally dst-sorted eix2.
// ---------------------------------------------------------------------------
__global__ __launch_bounds__(256) void bucket_sort(
    const int2* __restrict__ eix, const int* __restrict__ boff,
    int2* __restrict__ eix2, int NB)
{
    __shared__ int h64[BNODES];
    __shared__ int cur64[BNODES];
    int bk = blockIdx.x;
    int s = boff[bk], e = boff[bk + 1];
    int tid = threadIdx.x;
    int nbase = bk << BSH;

    if (tid < BNODES) h64[tid] = 0;
    __syncthreads();
    for (int i = s + tid; i < e; i += 256)
        atomicAdd(&h64[eix[i].y - nbase], 1);
    __syncthreads();
    if (tid < BNODES) {
        int v = h64[tid];
        int inc = v;
        for (int d2 = 1; d2 < BNODES; d2 <<= 1) {   // wave-level inclusive scan
            int t = __shfl_up(inc, d2);
            if (tid >= d2) inc += t;
        }
        cur64[tid] = inc - v;                        // exclusive prefix
    }
    __syncthreads();
    for (int i = s + tid; i < e; i += 256) {
        int2 ed = eix[i];
        int slot = atomicAdd(&cur64[ed.y - nbase], 1);
        eix2[s + slot] = ed;
    }
}

// ---------------------------------------------------------------------------
// Edge MLP via MFMA — barrier-free wave-independent tiles + register pipeline
// (r10 structure, best measured: 144.5us, bank conflicts 0, VGPR 108).
//
// Ledger: r0 192 lockstep; r1/r9 forced-occ SPILL; r5 occ-lockstep dead;
// r6 prefetch-lockstep neutral; r8 barrier-free 154; r10 reg-pipeline 144.5;
// r14 2-way ILP NEUTRAL (147.5, conflicts 6M) => edge is throughput-bound on
// the LDS pipe, not latency; further per-round edge gains <=5%. r17 shifts
// effort to the ~240us OUTSIDE the edge kernel.
// ---------------------------------------------------------------------------
__global__ __launch_bounds__(256, 2) void edge_mfma_kernel(
    const float* __restrict__ x,
    const float* __restrict__ We1, const float* __restrict__ be1,
    const float* __restrict__ We2, const float* __restrict__ be2,
    const int2* __restrict__ eix,
    float* __restrict__ hneigh, int N, int E, int T)
{
    __shared__ __attribute__((aligned(16))) float XCs[4][16 * 68];  // 17.4KB
    __shared__ __attribute__((aligned(16))) f16   Hbs[4][16 * 64];  // 8KB
    __shared__ int edsts[4][16];                                    // 256B

    const int tid  = threadIdx.x;
    const int w    = tid >> 6;
    const int lane = tid & 63;
    const int l15  = lane & 15;
    const int quad = lane >> 4;

    float* XC  = XCs[w];
    f16*   Hb  = Hbs[w];
    int*   edst = edsts[w];

    // Full weight sets in registers: wb1 (64 VGPR), wb2 (32 VGPR).
    f16x8 wb1[4][4];
#pragma unroll
    for (int kt = 0; kt < 4; ++kt)
#pragma unroll
        for (int nf = 0; nf < 4; ++nf) {
            int n = nf * 16 + l15;
#pragma unroll
            for (int j = 0; j < 8; ++j)
                wb1[kt][nf][j] = (f16)We1[(kt * 32 + quad * 8 + j) * 64 + n];
        }
    f16x8 wb2[2][4];
#pragma unroll
    for (int kt = 0; kt < 2; ++kt)
#pragma unroll
        for (int nf = 0; nf < 4; ++nf) {
            int n = nf * 16 + l15;
#pragma unroll
            for (int j = 0; j < 8; ++j)
                wb2[kt][nf][j] = (f16)We2[(kt * 32 + quad * 8 + j) * 64 + n];
        }

    float b1v[4], b2v[4];
#pragma unroll
    for (int nf = 0; nf < 4; ++nf) {
        b1v[nf] = be1[nf * 16 + l15];
        b2v[nf] = be2[nf * 16 + l15];
    }

    const int wid = blockIdx.x * 4 + w;   // global wave id
    const int nw  = gridDim.x * 4;

    // ---- pipeline prologue: tile0's x rows + tile1's edge indices ----
    int2 peC = eix[min(wid * 16 + l15, E - 1)];
    float4 s0, s1, s2, s3, d0v, d1v, d2v, d3v;
    {
        const float* ps = x + (size_t)peC.x * D;
        const float* pd = x + (size_t)peC.y * D;
        s0  = *(const float4*)(ps + quad * 8);
        s1  = *(const float4*)(ps + quad * 8 + 4);
        s2  = *(const float4*)(ps + 32 + quad * 8);
        s3  = *(const float4*)(ps + 32 + quad * 8 + 4);
        d0v = *(const float4*)(pd + quad * 8);
        d1v = *(const float4*)(pd + quad * 8 + 4);
        d2v = *(const float4*)(pd + 32 + quad * 8);
        d3v = *(const float4*)(pd + 32 + quad * 8 + 4);
    }
    int2 peN = eix[min((wid + nw) * 16 + l15, E - 1)];

    for (int tile = wid; tile < T; tile += nw) {
        const int e0 = tile * 16;

        int prevD = (e0 > 0)      ? eix[e0 - 1].y  : -2;   // wave-uniform
        int nextD = (e0 + 16 < E) ? eix[e0 + 16].y : -2;   // wave-uniform

        // ---- stage current tile (all from registers) ----
        *(float4*)&XC[l15 * 68 + quad * 8]          = s0;
        *(float4*)&XC[l15 * 68 + quad * 8 + 4]      = s1;
        *(float4*)&XC[l15 * 68 + 32 + quad * 8]     = s2;
        *(float4*)&XC[l15 * 68 + 32 + quad * 8 + 4] = s3;
        if (quad == 0) edst[l15] = (e0 + l15 < E) ? peC.y : N;

        f16x8 ah[4];
        ah[0][0]=(f16)s0.x; ah[0][1]=(f16)s0.y; ah[0][2]=(f16)s0.z; ah[0][3]=(f16)s0.w;
        ah[0][4]=(f16)s1.x; ah[0][5]=(f16)s1.y; ah[0][6]=(f16)s1.z; ah[0][7]=(f16)s1.w;
        ah[1][0]=(f16)s2.x; ah[1][1]=(f16)s2.y; ah[1][2]=(f16)s2.z; ah[1][3]=(f16)s2.w;
        ah[1][4]=(f16)s3.x; ah[1][5]=(f16)s3.y; ah[1][6]=(f16)s3.z; ah[1][7]=(f16)s3.w;
        ah[2][0]=(f16)d0v.x; ah[2][1]=(f16)d0v.y; ah[2][2]=(f16)d0v.z; ah[2][3]=(f16)d0v.w;
        ah[2][4]=(f16)d1v.x; ah[2][5]=(f16)d1v.y; ah[2][6]=(f16)d1v.z; ah[2][7]=(f16)d1v.w;
        ah[3][0]=(f16)d2v.x; ah[3][1]=(f16)d2v.y; ah[3][2]=(f16)d2v.z; ah[3][3]=(f16)d2v.w;
        ah[3][4]=(f16)d3v.x; ah[3][5]=(f16)d3v.y; ah[3][6]=(f16)d3v.z; ah[3][7]=(f16)d3v.w;

        // ---- prefetch: x rows for tile+nw, eix for tile+2nw ----
        float4 t0, t1, t2, t3, u0, u1, u2, u3;
        int2 peN2;
        {
            const float* ps2 = x + (size_t)peN.x * D;
            const float* pd2 = x + (size_t)peN.y * D;
            t0 = *(const float4*)(ps2 + quad * 8);
            t1 = *(const float4*)(ps2 + quad * 8 + 4);
            t2 = *(const float4*)(ps2 + 32 + quad * 8);
            t3 = *(const float4*)(ps2 + 32 + quad * 8 + 4);
            u0 = *(const float4*)(pd2 + quad * 8);
            u1 = *(const float4*)(pd2 + quad * 8 + 4);
            u2 = *(const float4*)(pd2 + 32 + quad * 8);
            u3 = *(const float4*)(pd2 + 32 + quad * 8 + 4);
            peN2 = eix[min((tile + 2 * nw) * 16 + l15, E - 1)];
        }

        // ---- GEMM1: [16,128]@[128,64] = 16 MFMA ----
        f32x4 acc[4] = {{0.f,0.f,0.f,0.f},{0.f,0.f,0.f,0.f},
                        {0.f,0.f,0.f,0.f},{0.f,0.f,0.f,0.f}};
#pragma unroll
        for (int kt = 0; kt < 4; ++kt)
#pragma unroll
            for (int nf = 0; nf < 4; ++nf)
                acc[nf] = __builtin_amdgcn_mfma_f32_16x16x32_f16(
                    ah[kt], wb1[kt][nf], acc[nf], 0, 0, 0);

        // ---- H = relu(acc+b1) -> Hbuf (ownership transpose) ----
#pragma unroll
        for (int nf = 0; nf < 4; ++nf)
#pragma unroll
            for (int i2 = 0; i2 < 4; ++i2)
                Hb[sw6(quad * 4 + i2, nf * 16 + l15)] =
                    (f16)fmaxf(acc[nf][i2] + b1v[nf], 0.f);

        // ---- GEMM2: [16,64]@[64,64] = 8 MFMA, A from Hbuf ----
        f32x4 dd[4] = {{0.f,0.f,0.f,0.f},{0.f,0.f,0.f,0.f},
                       {0.f,0.f,0.f,0.f},{0.f,0.f,0.f,0.f}};
#pragma unroll
        for (int kt = 0; kt < 2; ++kt) {
            f16x8 ah2 = *(const f16x8*)&Hb[sw6(l15, kt * 32 + quad * 8)];
#pragma unroll
            for (int nf = 0; nf < 4; ++nf)
                dd[nf] = __builtin_amdgcn_mfma_f32_16x16x32_f16(
                    ah2, wb2[kt][nf], dd[nf], 0, 0, 0);
        }

        // ---- contrib = xs * (d + b2), in-place in XC ----
#pragma unroll
        for (int nf = 0; nf < 4; ++nf)
#pragma unroll
            for (int i2 = 0; i2 < 4; ++i2) {
                int a = (quad * 4 + i2) * 68 + nf * 16 + l15;
                XC[a] = (dd[nf][i2] + b2v[nf]) * XC[a];
            }

        // ---- segmented sum over sorted dst runs (all 64 lanes = feature) ----
        {
            int j = lane;
            float a = 0.f;
            int cur = edst[0];
            int runStart = 0;
#pragma unroll
            for (int ii = 0; ii < 16; ++ii) {
                a += XC[ii * 68 + j];
                int nxt = (ii < 15) ? edst[ii + 1] : -3;
                if (nxt != cur) {
                    bool firstRun = (runStart == 0);
                    bool lastRun = (ii == 15) || (nxt >= N);
                    bool complete = (!firstRun || prevD != cur) &&
                                    (!lastRun || nextD != cur);
                    if (complete) hneigh[(size_t)cur * D + j] = a;
                    else atomicAdd(&hneigh[(size_t)cur * D + j], a);
                    a = 0.f; cur = nxt; runStart = ii + 1;
                }
            }
        }

        // ---- rotate pipeline registers ----
        s0 = t0; s1 = t1; s2 = t2; s3 = t3;
        d0v = u0; d1v = u1; d2v = u2; d3v = u3;
        peC = peN; peN = peN2;
        // NO barrier — stores retire asynchronously; next tile proceeds.
    }
}

// ---------------------------------------------------------------------------
// Node MLP via MFMA, weights in VGPR fragments, 2-term split.
// Grid = exact tile count (no stride imbalance).
// ---------------------------------------------------------------------------
__global__ __launch_bounds__(256, 4) void node_mfma_kernel(
    float* __restrict__ h,
    const float* __restrict__ Wn, const float* __restrict__ bn,
    const float* __restrict__ Wg, const float* __restrict__ bg,
    float* __restrict__ gate, int N, int T)
{
    __shared__ __attribute__((aligned(16))) f16 ANhi[64 * 64];
    __shared__ __attribute__((aligned(16))) f16 ANlo[64 * 64];

    const int tid = threadIdx.x;
    const int w = tid >> 6;
    const int lane = tid & 63;
    const int l15 = lane & 15;
    const int quad = lane >> 4;
    const int m0 = w * 16;

    f16x8 wn[2][4];
#pragma unroll
    for (int kt = 0; kt < 2; ++kt)
#pragma unroll
        for (int nf = 0; nf < 4; ++nf) {
            int n = nf * 16 + l15;
#pragma unroll
            for (int j = 0; j < 8; ++j)
                wn[kt][nf][j] = (f16)Wn[(kt * 32 + quad * 8 + j) * 64 + n];
        }

    float bnv[4], wgv[4];
#pragma unroll
    for (int nt = 0; nt < 4; ++nt) {
        bnv[nt] = bn[nt * 16 + l15];
        wgv[nt] = Wg[nt * 16 + l15];
    }
    const float bgv = bg[0];

    for (int tile = blockIdx.x; tile < T; tile += gridDim.x) {
        const int t0 = tile * 64;

        {
            int i = tid >> 2;
            int q = tid & 3;
            int node = min(t0 + i, N - 1);
            const float* p = h + (size_t)node * D + q * 16;
#pragma unroll
            for (int r = 0; r < 4; ++r) {
                float4 v = *(const float4*)(p + r * 4);
                int k = q * 16 + r * 4;
                f16x4 hv, lv;
                hv[0] = (f16)v.x; lv[0] = (f16)(v.x - (float)hv[0]);
                hv[1] = (f16)v.y; lv[1] = (f16)(v.y - (float)hv[1]);
                hv[2] = (f16)v.z; lv[2] = (f16)(v.z - (float)hv[2]);
                hv[3] = (f16)v.w; lv[3] = (f16)(v.w - (float)hv[3]);
                *(f16x4*)&ANhi[sw6(i, k)] = hv;
                *(f16x4*)&ANlo[sw6(i, k)] = lv;
            }
        }
        __syncthreads();

        f32x4 cacc[4] = {{0.f,0.f,0.f,0.f},{0.f,0.f,0.f,0.f},{0.f,0.f,0.f,0.f},{0.f,0.f,0.f,0.f}};
#pragma unroll
        for (int kt = 0; kt < 2; ++kt) {
            int k = kt * 32 + quad * 8;
            f16x8 ah = *(const f16x8*)&ANhi[sw6(m0 + l15, k)];
            f16x8 al = *(const f16x8*)&ANlo[sw6(m0 + l15, k)];
#pragma unroll
            for (int nf = 0; nf < 4; ++nf) {
                cacc[nf] = __builtin_amdgcn_mfma_f32_16x16x32_f16(ah, wn[kt][nf], cacc[nf], 0, 0, 0);
                cacc[nf] = __builtin_amdgcn_mfma_f32_16x16x32_f16(al, wn[kt][nf], cacc[nf], 0, 0, 0);
            }
        }
        __syncthreads();

        float gpart[4] = {0.f, 0.f, 0.f, 0.f};
#pragma unroll
        for (int nt = 0; nt < 4; ++nt) {
            int n = nt * 16 + l15;
#pragma unroll
            for (int i2 = 0; i2 < 4; ++i2) {
                int m = t0 + m0 + quad * 4 + i2;
                float v = fmaxf(cacc[nt][i2] + bnv[nt], 0.f);
                if (m < N) h[(size_t)m * D + n] = v;
                gpart[i2] += v * wgv[nt];
            }
        }
#pragma unroll
        for (int s = 1; s < 16; s <<= 1) {
#pragma unroll
            for (int i2 = 0; i2 < 4; ++i2) gpart[i2] += __shfl_xor(gpart[i2], s);
        }
        if (l15 == 0) {
#pragma unroll
            for (int i2 = 0; i2 < 4; ++i2) {
                int m = t0 + m0 + quad * 4 + i2;
                if (m < N) gate[m] = gpart[i2] + bgv;
            }
        }
    }
}

// ---------------------------------------------------------------------------
// Pool: one block per graph; softmax over gates, weighted sum, classifier.
// r17: weighted-sum loop unrolled x2 with independent accumulators (pool is
// latency-bound: 128 blocks = half the CUs, 1 wave/SIMD).
// ---------------------------------------------------------------------------
__global__ __launch_bounds__(256) void pool_kernel(
    const float* __restrict__ h2,
    const float* __restrict__ gate,
    const int* __restrict__ gid,
    const float* __restrict__ Wfc, const float* __restrict__ bfc,
    float* __restrict__ out, int N, int C)
{
    int g = blockIdx.x;
    int tid = threadIdx.x;

    int lo = 0, hi = N;
    while (lo < hi) { int mid = (lo + hi) >> 1; if (gid[mid] < g) lo = mid + 1; else hi = mid; }
    int s = lo;
    hi = N;
    while (lo < hi) { int mid = (lo + hi) >> 1; if (gid[mid] < g + 1) lo = mid + 1; else hi = mid; }
    int e = lo;

    __shared__ float red[256];
    __shared__ float accs[4][D];
    __shared__ float dens[4];

    float m = -INFINITY;
    for (int i = s + tid; i < e; i += 256) m = fmaxf(m, gate[i]);
    red[tid] = m;
    __syncthreads();
    for (int w = 128; w > 0; w >>= 1) {
        if (tid < w) red[tid] = fmaxf(red[tid], red[tid + w]);
        __syncthreads();
    }
    float gmax = red[0];
    __syncthreads();

    int f = tid & (D - 1);
    int grp = tid >> 6;
    float acc0 = 0.0f, den0 = 0.0f, acc1 = 0.0f, den1 = 0.0f;
    int i = s + grp;
    for (; i + 4 < e; i += 8) {
        float w0 = expf(gate[i] - gmax);
        float w1 = expf(gate[i + 4] - gmax);
        acc0 += w0 * h2[(size_t)i * D + f];
        acc1 += w1 * h2[(size_t)(i + 4) * D + f];
        if (f == 0) { den0 += w0; den1 += w1; }
    }
    for (; i < e; i += 4) {
        float w0 = expf(gate[i] - gmax);
        acc0 += w0 * h2[(size_t)i * D + f];
        if (f == 0) den0 += w0;
    }
    accs[grp][f] = acc0 + acc1;
    if (f == 0) dens[grp] = den0 + den1;
    __syncthreads();

    if (tid < D) {
        float p = accs[0][tid] + accs[1][tid] + accs[2][tid] + accs[3][tid];
        float dn = dens[0] + dens[1] + dens[2] + dens[3];
        p = (e > s) ? (p / dn) : 0.0f;
        red[tid] = p;
    }
    __syncthreads();

    if (tid < C) {
        float o = bfc[tid];
#pragma unroll
        for (int k = 0; k < D; ++k) o += red[k] * Wfc[k * C + tid];
        out[g * C + tid] = o;
    }
}

extern "C" void kernel_launch(void* const* d_in, const int* in_sizes, int n_in,
                              void* d_out, int out_size, void* d_ws, size_t ws_size,
                              hipStream_t stream) {
    const float* x   = (const float*)d_in[0];
    const float* We1 = (const float*)d_in[1];
    const float* be1 = (const float*)d_in[2];
    const float* We2 = (const float*)d_in[3];
    const float* be2 = (const float*)d_in[4];
    const float* Wn  = (const float*)d_in[5];
    const float* bn  = (const float*)d_in[6];
    const float* Wg  = (const float*)d_in[7];
    const float* bg  = (const float*)d_in[8];
    const float* Wfc = (const float*)d_in[9];
    const float* bfc = (const float*)d_in[10];
    const int* src = (const int*)d_in[11];
    const int* dst = (const int*)d_in[12];
    const int* gid = (const int*)d_in[13];

    const int N = in_sizes[0] / D;
    const int E = in_sizes[11];
    const int C = 10;
    const int G = out_size / C;
    const int NB = (N + BNODES - 1) / BNODES;

    // workspace: eix2 | union{eixA, hneigh} | gate | bucket arrays
    int2*  eix2   = (int2*)d_ws;                          // [E]      12.8MB
    int2*  eixA   = eix2 + E;                             // [E]      12.8MB
    float* hneigh = (float*)eixA;                         // [(N+1)*64] 25.6MB (overlay)
    float* gate   = hneigh + (size_t)(N + 1) * D;         // [N]
    int*   bhist  = (int*)(gate + N);                     // [NB]
    int*   boff   = bhist + NB;                           // [NB+1]
    int*   bcursor= boff + NB + 1;                        // [NB]
    float* outp   = (float*)d_out;

    const int Bh = (E + EB - 1) / EB;
    const int Te = (E + 15) / 16;     // 16-edge tiles, one wave each
    const int Tn = (N + 63) / 64;

    hipMemsetAsync(bhist, 0, (size_t)NB * sizeof(int), stream);

    // fused hist+scan+fill (cooperative: grid.sync between phases)
    {
        const int* dst_a = dst;
        const int* src_a = src;
        int E_a = E, NB_a = NB;
        void* args[] = {(void*)&dst_a, (void*)&src_a, (void*)&bhist,
                        (void*)&boff, (void*)&bcursor, (void*)&eixA,
                        (void*)&E_a, (void*)&NB_a};
        hipLaunchCooperativeKernel((const void*)bucket_prep,
                                   dim3(Bh), dim3(256), args, 0, stream);
    }
    bucket_sort<<<NB, 256, 0, stream>>>(eixA, boff, eix2, NB);

    // eixA dead; zero hneigh (overlay) before edge kernel
    hipMemsetAsync(hneigh, 0, (size_t)(N + 1) * D * sizeof(float), stream);

    edge_mfma_kernel<<<512, 256, 0, stream>>>(x, We1, be1, We2, be2,
                                              eix2, hneigh, N, E, Te);
    node_mfma_kernel<<<Tn, 256, 0, stream>>>(hneigh, Wn, bn, Wg, bg, gate, N, Tn);
    pool_kernel<<<G, 256, 0, stream>>>(hneigh, gate, gid, Wfc, bfc, outp, N, C);
}

// Round 18
// 350.600 us; speedup vs baseline: 1.3110x; 1.3110x over previous
//
#include <hip/hip_runtime.h>
#include <hip/hip_bf16.h>

#define D 64
#define BSH 6            // log2(nodes per bucket)
#define BNODES 64
#define NBMAX 2048       // LDS hist capacity (N <= 131072)
#define EB 4096          // edges per hist/fill block
#define PPARTS 4         // pool partial blocks per graph

typedef _Float16 f16;
typedef _Float16 f16x4 __attribute__((ext_vector_type(4)));
typedef _Float16 f16x8 __attribute__((ext_vector_type(8)));
typedef float f32x4 __attribute__((ext_vector_type(4)));

__device__ __forceinline__ int sw6(int m, int k) {  // row stride 64 f16
    return (m << 6) + ((((k >> 3) ^ (m & 7)) & 7) << 3) + (k & 7);
}

// ---------------------------------------------------------------------------
// Bucket partition (coarse sort by dst>>6) — two-level LDS histograms.
// (r18: cooperative fusion REVERTED — r17 showed +75us from coop launch.)
// ---------------------------------------------------------------------------
__global__ __launch_bounds__(256) void bucket_hist(
    const int* __restrict__ dst, int* __restrict__ bhist, int E, int NB)
{
    __shared__ int lhist[NBMAX];
    int tid = threadIdx.x;
    for (int b = tid; b < NB; b += 256) lhist[b] = 0;
    __syncthreads();
    int base = blockIdx.x * EB;
#pragma unroll
    for (int r = 0; r < EB / 256; ++r) {
        int e = base + r * 256 + tid;
        if (e < E) atomicAdd(&lhist[dst[e] >> BSH], 1);
    }
    __syncthreads();
    for (int b = tid; b < NB; b += 256) {
        int v = lhist[b];
        if (v) atomicAdd(&bhist[b], v);
    }
}

__global__ __launch_bounds__(256) void bucket_scan(
    const int* __restrict__ bhist, int* __restrict__ boff,
    int* __restrict__ bcursor, int NB)
{
    __shared__ int lds[256];
    int tid = threadIdx.x;
    int chunk = (NB + 255) / 256;
    int b0 = tid * chunk;
    int b1 = min(b0 + chunk, NB);
    int s = 0;
    for (int b = b0; b < b1; ++b) s += bhist[b];
    lds[tid] = s;
    __syncthreads();
    for (int d2 = 1; d2 < 256; d2 <<= 1) {
        int v = (tid >= d2) ? lds[tid - d2] : 0;
        __syncthreads();
        lds[tid] += v;
        __syncthreads();
    }
    int run = (tid == 0) ? 0 : lds[tid - 1];
    for (int b = b0; b < b1; ++b) {
        boff[b] = run;
        bcursor[b] = run;
        run += bhist[b];
    }
    if (tid == 255) boff[NB] = lds[255];
}

__global__ __launch_bounds__(256) void bucket_fill(
    const int* __restrict__ dst, const int* __restrict__ src,
    int* __restrict__ bcursor, int2* __restrict__ eix, int E, int NB)
{
    __shared__ int lhist[NBMAX];
    __shared__ int lcur[NBMAX];
    int tid = threadIdx.x;
    for (int b = tid; b < NB; b += 256) lhist[b] = 0;
    __syncthreads();
    int base = blockIdx.x * EB;
    int dv[EB / 256];
#pragma unroll
    for (int r = 0; r < EB / 256; ++r) {
        int e = base + r * 256 + tid;
        dv[r] = (e < E) ? dst[e] : -1;
        if (dv[r] >= 0) atomicAdd(&lhist[dv[r] >> BSH], 1);
    }
    __syncthreads();
    for (int b = tid; b < NB; b += 256) {
        int v = lhist[b];
        lcur[b] = v ? atomicAdd(&bcursor[b], v) : 0;
    }
    __syncthreads();
#pragma unroll
    for (int r = 0; r < EB / 256; ++r) {
        int e = base + r * 256 + tid;
        if (dv[r] >= 0) {
            int p = atomicAdd(&lcur[dv[r] >> BSH], 1);
            eix[p] = make_int2(src[e], dv[r]);
        }
    }
}

// ---------------------------------------------------------------------------
// Per-bucket exact counting sort (64 bins in LDS) -> globally dst-sorted eix2.
// ---------------------------------------------------------------------------
__global__ __launch_bounds__(256) void bucket_sort(
    const int2* __restrict__ eix, const int* __restrict__ boff,
    int2* __restrict__ eix2, int NB)
{
    __shared__ int h64[BNODES];
    __shared__ int cur64[BNODES];
    int bk = blockIdx.x;
    int s = boff[bk], e = boff[bk + 1];
    int tid = threadIdx.x;
    int nbase = bk << BSH;

    if (tid < BNODES) h64[tid] = 0;
    __syncthreads();
    for (int i = s + tid; i < e; i += 256)
        atomicAdd(&h64[eix[i].y - nbase], 1);
    __syncthreads();
    if (tid < BNODES) {
        int v = h64[tid];
        int inc = v;
        for (int d2 = 1; d2 < BNODES; d2 <<= 1) {   // wave-level inclusive scan
            int t = __shfl_up(inc, d2);
            if (tid >= d2) inc += t;
        }
        cur64[tid] = inc - v;                        // exclusive prefix
    }
    __syncthreads();
    for (int i = s + tid; i < e; i += 256) {
        int2 ed = eix[i];
        int slot = atomicAdd(&cur64[ed.y - nbase], 1);
        eix2[s + slot] = ed;
    }
}

// ---------------------------------------------------------------------------
// Edge MLP via MFMA — barrier-free wave-independent tiles + register pipeline
// (r10 structure, best measured: 144.5us, bank conflicts 0, VGPR 108).
//
// Ledger: r0 192 lockstep; r1/r9 forced-occ SPILL; r5 occ-lockstep dead;
// r6 prefetch-lockstep neutral; r8 barrier-free 154; r10 reg-pipeline 144.5;
// r14 2-way ILP neutral (LDS-pipe-bound); r17 coop-fusion REGRESSED (+75us).
// Edge is throughput-saturated; r18 targets the pool (largest non-edge cost).
// ---------------------------------------------------------------------------
__global__ __launch_bounds__(256, 2) void edge_mfma_kernel(
    const float* __restrict__ x,
    const float* __restrict__ We1, const float* __restrict__ be1,
    const float* __restrict__ We2, const float* __restrict__ be2,
    const int2* __restrict__ eix,
    float* __restrict__ hneigh, int N, int E, int T)
{
    __shared__ __attribute__((aligned(16))) float XCs[4][16 * 68];  // 17.4KB
    __shared__ __attribute__((aligned(16))) f16   Hbs[4][16 * 64];  // 8KB
    __shared__ int edsts[4][16];                                    // 256B

    const int tid  = threadIdx.x;
    const int w    = tid >> 6;
    const int lane = tid & 63;
    const int l15  = lane & 15;
    const int quad = lane >> 4;

    float* XC  = XCs[w];
    f16*   Hb  = Hbs[w];
    int*   edst = edsts[w];

    // Full weight sets in registers: wb1 (64 VGPR), wb2 (32 VGPR).
    f16x8 wb1[4][4];
#pragma unroll
    for (int kt = 0; kt < 4; ++kt)
#pragma unroll
        for (int nf = 0; nf < 4; ++nf) {
            int n = nf * 16 + l15;
#pragma unroll
            for (int j = 0; j < 8; ++j)
                wb1[kt][nf][j] = (f16)We1[(kt * 32 + quad * 8 + j) * 64 + n];
        }
    f16x8 wb2[2][4];
#pragma unroll
    for (int kt = 0; kt < 2; ++kt)
#pragma unroll
        for (int nf = 0; nf < 4; ++nf) {
            int n = nf * 16 + l15;
#pragma unroll
            for (int j = 0; j < 8; ++j)
                wb2[kt][nf][j] = (f16)We2[(kt * 32 + quad * 8 + j) * 64 + n];
        }

    float b1v[4], b2v[4];
#pragma unroll
    for (int nf = 0; nf < 4; ++nf) {
        b1v[nf] = be1[nf * 16 + l15];
        b2v[nf] = be2[nf * 16 + l15];
    }

    const int wid = blockIdx.x * 4 + w;   // global wave id
    const int nw  = gridDim.x * 4;

    // ---- pipeline prologue: tile0's x rows + tile1's edge indices ----
    int2 peC = eix[min(wid * 16 + l15, E - 1)];
    float4 s0, s1, s2, s3, d0v, d1v, d2v, d3v;
    {
        const float* ps = x + (size_t)peC.x * D;
        const float* pd = x + (size_t)peC.y * D;
        s0  = *(const float4*)(ps + quad * 8);
        s1  = *(const float4*)(ps + quad * 8 + 4);
        s2  = *(const float4*)(ps + 32 + quad * 8);
        s3  = *(const float4*)(ps + 32 + quad * 8 + 4);
        d0v = *(const float4*)(pd + quad * 8);
        d1v = *(const float4*)(pd + quad * 8 + 4);
        d2v = *(const float4*)(pd + 32 + quad * 8);
        d3v = *(const float4*)(pd + 32 + quad * 8 + 4);
    }
    int2 peN = eix[min((wid + nw) * 16 + l15, E - 1)];

    for (int tile = wid; tile < T; tile += nw) {
        const int e0 = tile * 16;

        int prevD = (e0 > 0)      ? eix[e0 - 1].y  : -2;   // wave-uniform
        int nextD = (e0 + 16 < E) ? eix[e0 + 16].y : -2;   // wave-uniform

        // ---- stage current tile (all from registers) ----
        *(float4*)&XC[l15 * 68 + quad * 8]          = s0;
        *(float4*)&XC[l15 * 68 + quad * 8 + 4]      = s1;
        *(float4*)&XC[l15 * 68 + 32 + quad * 8]     = s2;
        *(float4*)&XC[l15 * 68 + 32 + quad * 8 + 4] = s3;
        if (quad == 0) edst[l15] = (e0 + l15 < E) ? peC.y : N;

        f16x8 ah[4];
        ah[0][0]=(f16)s0.x; ah[0][1]=(f16)s0.y; ah[0][2]=(f16)s0.z; ah[0][3]=(f16)s0.w;
        ah[0][4]=(f16)s1.x; ah[0][5]=(f16)s1.y; ah[0][6]=(f16)s1.z; ah[0][7]=(f16)s1.w;
        ah[1][0]=(f16)s2.x; ah[1][1]=(f16)s2.y; ah[1][2]=(f16)s2.z; ah[1][3]=(f16)s2.w;
        ah[1][4]=(f16)s3.x; ah[1][5]=(f16)s3.y; ah[1][6]=(f16)s3.z; ah[1][7]=(f16)s3.w;
        ah[2][0]=(f16)d0v.x; ah[2][1]=(f16)d0v.y; ah[2][2]=(f16)d0v.z; ah[2][3]=(f16)d0v.w;
        ah[2][4]=(f16)d1v.x; ah[2][5]=(f16)d1v.y; ah[2][6]=(f16)d1v.z; ah[2][7]=(f16)d1v.w;
        ah[3][0]=(f16)d2v.x; ah[3][1]=(f16)d2v.y; ah[3][2]=(f16)d2v.z; ah[3][3]=(f16)d2v.w;
        ah[3][4]=(f16)d3v.x; ah[3][5]=(f16)d3v.y; ah[3][6]=(f16)d3v.z; ah[3][7]=(f16)d3v.w;

        // ---- prefetch: x rows for tile+nw, eix for tile+2nw ----
        float4 t0, t1, t2, t3, u0, u1, u2, u3;
        int2 peN2;
        {
            const float* ps2 = x + (size_t)peN.x * D;
            const float* pd2 = x + (size_t)peN.y * D;
            t0 = *(const float4*)(ps2 + quad * 8);
            t1 = *(const float4*)(ps2 + quad * 8 + 4);
            t2 = *(const float4*)(ps2 + 32 + quad * 8);
            t3 = *(const float4*)(ps2 + 32 + quad * 8 + 4);
            u0 = *(const float4*)(pd2 + quad * 8);
            u1 = *(const float4*)(pd2 + quad * 8 + 4);
            u2 = *(const float4*)(pd2 + 32 + quad * 8);
            u3 = *(const float4*)(pd2 + 32 + quad * 8 + 4);
            peN2 = eix[min((tile + 2 * nw) * 16 + l15, E - 1)];
        }

        // ---- GEMM1: [16,128]@[128,64] = 16 MFMA ----
        f32x4 acc[4] = {{0.f,0.f,0.f,0.f},{0.f,0.f,0.f,0.f},
                        {0.f,0.f,0.f,0.f},{0.f,0.f,0.f,0.f}};
#pragma unroll
        for (int kt = 0; kt < 4; ++kt)
#pragma unroll
            for (int nf = 0; nf < 4; ++nf)
                acc[nf] = __builtin_amdgcn_mfma_f32_16x16x32_f16(
                    ah[kt], wb1[kt][nf], acc[nf], 0, 0, 0);

        // ---- H = relu(acc+b1) -> Hbuf (ownership transpose) ----
#pragma unroll
        for (int nf = 0; nf < 4; ++nf)
#pragma unroll
            for (int i2 = 0; i2 < 4; ++i2)
                Hb[sw6(quad * 4 + i2, nf * 16 + l15)] =
                    (f16)fmaxf(acc[nf][i2] + b1v[nf], 0.f);

        // ---- GEMM2: [16,64]@[64,64] = 8 MFMA, A from Hbuf ----
        f32x4 dd[4] = {{0.f,0.f,0.f,0.f},{0.f,0.f,0.f,0.f},
                       {0.f,0.f,0.f,0.f},{0.f,0.f,0.f,0.f}};
#pragma unroll
        for (int kt = 0; kt < 2; ++kt) {
            f16x8 ah2 = *(const f16x8*)&Hb[sw6(l15, kt * 32 + quad * 8)];
#pragma unroll
            for (int nf = 0; nf < 4; ++nf)
                dd[nf] = __builtin_amdgcn_mfma_f32_16x16x32_f16(
                    ah2, wb2[kt][nf], dd[nf], 0, 0, 0);
        }

        // ---- contrib = xs * (d + b2), in-place in XC ----
#pragma unroll
        for (int nf = 0; nf < 4; ++nf)
#pragma unroll
            for (int i2 = 0; i2 < 4; ++i2) {
                int a = (quad * 4 + i2) * 68 + nf * 16 + l15;
                XC[a] = (dd[nf][i2] + b2v[nf]) * XC[a];
            }

        // ---- segmented sum over sorted dst runs (all 64 lanes = feature) ----
        {
            int j = lane;
            float a = 0.f;
            int cur = edst[0];
            int runStart = 0;
#pragma unroll
            for (int ii = 0; ii < 16; ++ii) {
                a += XC[ii * 68 + j];
                int nxt = (ii < 15) ? edst[ii + 1] : -3;
                if (nxt != cur) {
                    bool firstRun = (runStart == 0);
                    bool lastRun = (ii == 15) || (nxt >= N);
                    bool complete = (!firstRun || prevD != cur) &&
                                    (!lastRun || nextD != cur);
                    if (complete) hneigh[(size_t)cur * D + j] = a;
                    else atomicAdd(&hneigh[(size_t)cur * D + j], a);
                    a = 0.f; cur = nxt; runStart = ii + 1;
                }
            }
        }

        // ---- rotate pipeline registers ----
        s0 = t0; s1 = t1; s2 = t2; s3 = t3;
        d0v = u0; d1v = u1; d2v = u2; d3v = u3;
        peC = peN; peN = peN2;
        // NO barrier — stores retire asynchronously; next tile proceeds.
    }
}

// ---------------------------------------------------------------------------
// Node MLP via MFMA, weights in VGPR fragments, 2-term split (r13 config).
// ---------------------------------------------------------------------------
__global__ __launch_bounds__(256, 4) void node_mfma_kernel(
    float* __restrict__ h,
    const float* __restrict__ Wn, const float* __restrict__ bn,
    const float* __restrict__ Wg, const float* __restrict__ bg,
    float* __restrict__ gate, int N, int T)
{
    __shared__ __attribute__((aligned(16))) f16 ANhi[64 * 64];
    __shared__ __attribute__((aligned(16))) f16 ANlo[64 * 64];

    const int tid = threadIdx.x;
    const int w = tid >> 6;
    const int lane = tid & 63;
    const int l15 = lane & 15;
    const int quad = lane >> 4;
    const int m0 = w * 16;

    f16x8 wn[2][4];
#pragma unroll
    for (int kt = 0; kt < 2; ++kt)
#pragma unroll
        for (int nf = 0; nf < 4; ++nf) {
            int n = nf * 16 + l15;
#pragma unroll
            for (int j = 0; j < 8; ++j)
                wn[kt][nf][j] = (f16)Wn[(kt * 32 + quad * 8 + j) * 64 + n];
        }

    float bnv[4], wgv[4];
#pragma unroll
    for (int nt = 0; nt < 4; ++nt) {
        bnv[nt] = bn[nt * 16 + l15];
        wgv[nt] = Wg[nt * 16 + l15];
    }
    const float bgv = bg[0];

    for (int tile = blockIdx.x; tile < T; tile += gridDim.x) {
        const int t0 = tile * 64;

        {
            int i = tid >> 2;
            int q = tid & 3;
            int node = min(t0 + i, N - 1);
            const float* p = h + (size_t)node * D + q * 16;
#pragma unroll
            for (int r = 0; r < 4; ++r) {
                float4 v = *(const float4*)(p + r * 4);
                int k = q * 16 + r * 4;
                f16x4 hv, lv;
                hv[0] = (f16)v.x; lv[0] = (f16)(v.x - (float)hv[0]);
                hv[1] = (f16)v.y; lv[1] = (f16)(v.y - (float)hv[1]);
                hv[2] = (f16)v.z; lv[2] = (f16)(v.z - (float)hv[2]);
                hv[3] = (f16)v.w; lv[3] = (f16)(v.w - (float)hv[3]);
                *(f16x4*)&ANhi[sw6(i, k)] = hv;
                *(f16x4*)&ANlo[sw6(i, k)] = lv;
            }
        }
        __syncthreads();

        f32x4 cacc[4] = {{0.f,0.f,0.f,0.f},{0.f,0.f,0.f,0.f},{0.f,0.f,0.f,0.f},{0.f,0.f,0.f,0.f}};
#pragma unroll
        for (int kt = 0; kt < 2; ++kt) {
            int k = kt * 32 + quad * 8;
            f16x8 ah = *(const f16x8*)&ANhi[sw6(m0 + l15, k)];
            f16x8 al = *(const f16x8*)&ANlo[sw6(m0 + l15, k)];
#pragma unroll
            for (int nf = 0; nf < 4; ++nf) {
                cacc[nf] = __builtin_amdgcn_mfma_f32_16x16x32_f16(ah, wn[kt][nf], cacc[nf], 0, 0, 0);
                cacc[nf] = __builtin_amdgcn_mfma_f32_16x16x32_f16(al, wn[kt][nf], cacc[nf], 0, 0, 0);
            }
        }
        __syncthreads();

        float gpart[4] = {0.f, 0.f, 0.f, 0.f};
#pragma unroll
        for (int nt = 0; nt < 4; ++nt) {
            int n = nt * 16 + l15;
#pragma unroll
            for (int i2 = 0; i2 < 4; ++i2) {
                int m = t0 + m0 + quad * 4 + i2;
                float v = fmaxf(cacc[nt][i2] + bnv[nt], 0.f);
                if (m < N) h[(size_t)m * D + n] = v;
                gpart[i2] += v * wgv[nt];
            }
        }
#pragma unroll
        for (int s = 1; s < 16; s <<= 1) {
#pragma unroll
            for (int i2 = 0; i2 < 4; ++i2) gpart[i2] += __shfl_xor(gpart[i2], s);
        }
        if (l15 == 0) {
#pragma unroll
            for (int i2 = 0; i2 < 4; ++i2) {
                int m = t0 + m0 + quad * 4 + i2;
                if (m < N) gate[m] = gpart[i2] + bgv;
            }
        }
    }
}

// ---------------------------------------------------------------------------
// Pool SPLIT (r18): pool was ~60-90us with only G=128 blocks (half the CUs
// idle, serial latency-bound row loop). pool_partial runs PPARTS blocks per
// graph, each computing a LOCAL-max softmax partial (m_p, den_p, acc_p[64]);
// pool_combine rescales by exp(m_p - m) and applies the classifier. Exact
// up to fp reassociation. Partials live in the dead eix2 workspace region.
// ---------------------------------------------------------------------------
__global__ __launch_bounds__(256) void pool_partial(
    const float* __restrict__ h2,
    const float* __restrict__ gate,
    const int* __restrict__ gid,
    float* __restrict__ pm, float* __restrict__ pden,
    float* __restrict__ pacc, int N)
{
    int gb = blockIdx.x;
    int g = gb / PPARTS;
    int p = gb % PPARTS;
    int tid = threadIdx.x;

    int lo = 0, hi = N;
    while (lo < hi) { int mid = (lo + hi) >> 1; if (gid[mid] < g) lo = mid + 1; else hi = mid; }
    int s = lo;
    hi = N;
    while (lo < hi) { int mid = (lo + hi) >> 1; if (gid[mid] < g + 1) lo = mid + 1; else hi = mid; }
    int e = lo;

    int len = e - s;
    int st = s + (int)(((long long)len * p) / PPARTS);
    int en = s + (int)(((long long)len * (p + 1)) / PPARTS);

    __shared__ float red[256];
    __shared__ float accs[4][D];
    __shared__ float dens[4];

    // local max over this part
    float m = -INFINITY;
    for (int i = st + tid; i < en; i += 256) m = fmaxf(m, gate[i]);
    red[tid] = m;
    __syncthreads();
    for (int w = 128; w > 0; w >>= 1) {
        if (tid < w) red[tid] = fmaxf(red[tid], red[tid + w]);
        __syncthreads();
    }
    float lmax = red[0];
    __syncthreads();

    // weighted sums with local max
    int f = tid & (D - 1);
    int grp = tid >> 6;
    float acc = 0.0f, den = 0.0f;
    for (int i = st + grp; i < en; i += 4) {
        float wv = expf(gate[i] - lmax);
        acc += wv * h2[(size_t)i * D + f];
        if (f == 0) den += wv;
    }
    accs[grp][f] = acc;
    if (f == 0) dens[grp] = den;
    __syncthreads();

    if (tid < D)
        pacc[(size_t)gb * D + tid] =
            accs[0][tid] + accs[1][tid] + accs[2][tid] + accs[3][tid];
    if (tid == 0) {
        pden[gb] = dens[0] + dens[1] + dens[2] + dens[3];
        pm[gb] = lmax;
    }
}

__global__ __launch_bounds__(64) void pool_combine(
    const float* __restrict__ pm, const float* __restrict__ pden,
    const float* __restrict__ pacc,
    const float* __restrict__ Wfc, const float* __restrict__ bfc,
    float* __restrict__ out, int C)
{
    int g = blockIdx.x;
    int tid = threadIdx.x;   // 64 threads

    __shared__ float red[D];

    float m = -INFINITY;
#pragma unroll
    for (int p = 0; p < PPARTS; ++p) m = fmaxf(m, pm[g * PPARTS + p]);

    float den = 0.f, pf = 0.f;
#pragma unroll
    for (int p = 0; p < PPARTS; ++p) {
        float mp = pm[g * PPARTS + p];
        float sc = (mp > -INFINITY) ? expf(mp - m) : 0.f;
        den += pden[g * PPARTS + p] * sc;
        pf  += pacc[(size_t)(g * PPARTS + p) * D + tid] * sc;
    }
    red[tid] = (den > 0.f) ? (pf / den) : 0.f;
    __syncthreads();

    if (tid < C) {
        float o = bfc[tid];
#pragma unroll
        for (int k = 0; k < D; ++k) o += red[k] * Wfc[k * C + tid];
        out[g * C + tid] = o;
    }
}

extern "C" void kernel_launch(void* const* d_in, const int* in_sizes, int n_in,
                              void* d_out, int out_size, void* d_ws, size_t ws_size,
                              hipStream_t stream) {
    const float* x   = (const float*)d_in[0];
    const float* We1 = (const float*)d_in[1];
    const float* be1 = (const float*)d_in[2];
    const float* We2 = (const float*)d_in[3];
    const float* be2 = (const float*)d_in[4];
    const float* Wn  = (const float*)d_in[5];
    const float* bn  = (const float*)d_in[6];
    const float* Wg  = (const float*)d_in[7];
    const float* bg  = (const float*)d_in[8];
    const float* Wfc = (const float*)d_in[9];
    const float* bfc = (const float*)d_in[10];
    const int* src = (const int*)d_in[11];
    const int* dst = (const int*)d_in[12];
    const int* gid = (const int*)d_in[13];

    const int N = in_sizes[0] / D;
    const int E = in_sizes[11];
    const int C = 10;
    const int G = out_size / C;
    const int NB = (N + BNODES - 1) / BNODES;

    // workspace: eix2 | union{eixA, hneigh} | gate | bucket arrays
    // eix2 is dead after the edge kernel -> pool partials overlay it.
    int2*  eix2   = (int2*)d_ws;                          // [E]      12.8MB
    int2*  eixA   = eix2 + E;                             // [E]      12.8MB
    float* hneigh = (float*)eixA;                         // [(N+1)*64] 25.6MB (overlay)
    float* gate   = hneigh + (size_t)(N + 1) * D;         // [N]
    int*   bhist  = (int*)(gate + N);                     // [NB]
    int*   boff   = bhist + NB;                           // [NB+1]
    int*   bcursor= boff + NB + 1;                        // [NB]
    float* outp   = (float*)d_out;

    float* pm   = (float*)eix2;                           // [G*PPARTS] (overlay, post-edge)
    float* pden = pm + (size_t)G * PPARTS;                // [G*PPARTS]
    float* pacc = pden + (size_t)G * PPARTS;              // [G*PPARTS*D]

    const int Bh = (E + EB - 1) / EB;
    const int Te = (E + 15) / 16;     // 16-edge tiles, one wave each
    const int Tn = (N + 63) / 64;

    hipMemsetAsync(bhist, 0, (size_t)NB * sizeof(int), stream);

    bucket_hist<<<Bh, 256, 0, stream>>>(dst, bhist, E, NB);
    bucket_scan<<<1, 256, 0, stream>>>(bhist, boff, bcursor, NB);
    bucket_fill<<<Bh, 256, 0, stream>>>(dst, src, bcursor, eixA, E, NB);
    bucket_sort<<<NB, 256, 0, stream>>>(eixA, boff, eix2, NB);

    // eixA dead; zero hneigh (overlay) before edge kernel
    hipMemsetAsync(hneigh, 0, (size_t)(N + 1) * D * sizeof(float), stream);

    edge_mfma_kernel<<<512, 256, 0, stream>>>(x, We1, be1, We2, be2,
                                              eix2, hneigh, N, E, Te);
    node_mfma_kernel<<<1024, 256, 0, stream>>>(hneigh, Wn, bn, Wg, bg, gate, N, Tn);
    pool_partial<<<G * PPARTS, 256, 0, stream>>>(hneigh, gate, gid,
                                                 pm, pden, pacc, N);
    pool_combine<<<G, 64, 0, stream>>>(pm, pden, pacc, Wfc, bfc, outp, C);
}

// Round 19
// 345.202 us; speedup vs baseline: 1.3315x; 1.0156x over previous
//
#include <hip/hip_runtime.h>
#include <hip/hip_bf16.h>

#define D 64
#define BSH 6            // log2(nodes per bucket)
#define BNODES 64
#define NBMAX 2048       // LDS hist capacity (N <= 131072)
#define EB 4096          // edges per hist/fill block
#define PPARTS 8         // pool partial blocks per graph (r19: 4->8)

typedef _Float16 f16;
typedef _Float16 f16x4 __attribute__((ext_vector_type(4)));
typedef _Float16 f16x8 __attribute__((ext_vector_type(8)));
typedef float f32x4 __attribute__((ext_vector_type(4)));

__device__ __forceinline__ int sw6(int m, int k) {  // row stride 64 f16
    return (m << 6) + ((((k >> 3) ^ (m & 7)) & 7) << 3) + (k & 7);
}

// ---------------------------------------------------------------------------
// Bucket partition (coarse sort by dst>>6) — two-level LDS histograms.
// ---------------------------------------------------------------------------
__global__ __launch_bounds__(256) void bucket_hist(
    const int* __restrict__ dst, int* __restrict__ bhist, int E, int NB)
{
    __shared__ int lhist[NBMAX];
    int tid = threadIdx.x;
    for (int b = tid; b < NB; b += 256) lhist[b] = 0;
    __syncthreads();
    int base = blockIdx.x * EB;
#pragma unroll
    for (int r = 0; r < EB / 256; ++r) {
        int e = base + r * 256 + tid;
        if (e < E) atomicAdd(&lhist[dst[e] >> BSH], 1);
    }
    __syncthreads();
    for (int b = tid; b < NB; b += 256) {
        int v = lhist[b];
        if (v) atomicAdd(&bhist[b], v);
    }
}

__global__ __launch_bounds__(256) void bucket_scan(
    const int* __restrict__ bhist, int* __restrict__ boff,
    int* __restrict__ bcursor, int NB)
{
    __shared__ int lds[256];
    int tid = threadIdx.x;
    int chunk = (NB + 255) / 256;
    int b0 = tid * chunk;
    int b1 = min(b0 + chunk, NB);
    int s = 0;
    for (int b = b0; b < b1; ++b) s += bhist[b];
    lds[tid] = s;
    __syncthreads();
    for (int d2 = 1; d2 < 256; d2 <<= 1) {
        int v = (tid >= d2) ? lds[tid - d2] : 0;
        __syncthreads();
        lds[tid] += v;
        __syncthreads();
    }
    int run = (tid == 0) ? 0 : lds[tid - 1];
    for (int b = b0; b < b1; ++b) {
        boff[b] = run;
        bcursor[b] = run;
        run += bhist[b];
    }
    if (tid == 255) boff[NB] = lds[255];
}

__global__ __launch_bounds__(256) void bucket_fill(
    const int* __restrict__ dst, const int* __restrict__ src,
    int* __restrict__ bcursor, int2* __restrict__ eix, int E, int NB)
{
    __shared__ int lhist[NBMAX];
    __shared__ int lcur[NBMAX];
    int tid = threadIdx.x;
    for (int b = tid; b < NB; b += 256) lhist[b] = 0;
    __syncthreads();
    int base = blockIdx.x * EB;
    int dv[EB / 256];
#pragma unroll
    for (int r = 0; r < EB / 256; ++r) {
        int e = base + r * 256 + tid;
        dv[r] = (e < E) ? dst[e] : -1;
        if (dv[r] >= 0) atomicAdd(&lhist[dv[r] >> BSH], 1);
    }
    __syncthreads();
    for (int b = tid; b < NB; b += 256) {
        int v = lhist[b];
        lcur[b] = v ? atomicAdd(&bcursor[b], v) : 0;
    }
    __syncthreads();
#pragma unroll
    for (int r = 0; r < EB / 256; ++r) {
        int e = base + r * 256 + tid;
        if (dv[r] >= 0) {
            int p = atomicAdd(&lcur[dv[r] >> BSH], 1);
            eix[p] = make_int2(src[e], dv[r]);
        }
    }
}

// ---------------------------------------------------------------------------
// Per-bucket exact counting sort (64 bins in LDS) -> globally dst-sorted eix2.
// ---------------------------------------------------------------------------
__global__ __launch_bounds__(256) void bucket_sort(
    const int2* __restrict__ eix, const int* __restrict__ boff,
    int2* __restrict__ eix2, int NB)
{
    __shared__ int h64[BNODES];
    __shared__ int cur64[BNODES];
    int bk = blockIdx.x;
    int s = boff[bk], e = boff[bk + 1];
    int tid = threadIdx.x;
    int nbase = bk << BSH;

    if (tid < BNODES) h64[tid] = 0;
    __syncthreads();
    for (int i = s + tid; i < e; i += 256)
        atomicAdd(&h64[eix[i].y - nbase], 1);
    __syncthreads();
    if (tid < BNODES) {
        int v = h64[tid];
        int inc = v;
        for (int d2 = 1; d2 < BNODES; d2 <<= 1) {   // wave-level inclusive scan
            int t = __shfl_up(inc, d2);
            if (tid >= d2) inc += t;
        }
        cur64[tid] = inc - v;                        // exclusive prefix
    }
    __syncthreads();
    for (int i = s + tid; i < e; i += 256) {
        int2 ed = eix[i];
        int slot = atomicAdd(&cur64[ed.y - nbase], 1);
        eix2[s + slot] = ed;
    }
}

// ---------------------------------------------------------------------------
// Edge MLP via MFMA — barrier-free wave-independent tiles + register pipeline
// (r10 structure, best measured: 144.5-145.4us, bank conflicts 0, VGPR 108).
//
// Ledger: r0 192 lockstep; r1/r9 forced-occ SPILL; r5 occ-lockstep dead;
// r6 prefetch-lockstep neutral; r8 barrier-free 154; r10 reg-pipeline 144.5;
// r14 2-way ILP neutral; r17 coop-fusion REGRESSED; r18 pool-split WIN
// (385->350.6). Edge throughput-saturated; r19 widens pool/node parallelism.
// ---------------------------------------------------------------------------
__global__ __launch_bounds__(256, 2) void edge_mfma_kernel(
    const float* __restrict__ x,
    const float* __restrict__ We1, const float* __restrict__ be1,
    const float* __restrict__ We2, const float* __restrict__ be2,
    const int2* __restrict__ eix,
    float* __restrict__ hneigh, int N, int E, int T)
{
    __shared__ __attribute__((aligned(16))) float XCs[4][16 * 68];  // 17.4KB
    __shared__ __attribute__((aligned(16))) f16   Hbs[4][16 * 64];  // 8KB
    __shared__ int edsts[4][16];                                    // 256B

    const int tid  = threadIdx.x;
    const int w    = tid >> 6;
    const int lane = tid & 63;
    const int l15  = lane & 15;
    const int quad = lane >> 4;

    float* XC  = XCs[w];
    f16*   Hb  = Hbs[w];
    int*   edst = edsts[w];

    // Full weight sets in registers: wb1 (64 VGPR), wb2 (32 VGPR).
    f16x8 wb1[4][4];
#pragma unroll
    for (int kt = 0; kt < 4; ++kt)
#pragma unroll
        for (int nf = 0; nf < 4; ++nf) {
            int n = nf * 16 + l15;
#pragma unroll
            for (int j = 0; j < 8; ++j)
                wb1[kt][nf][j] = (f16)We1[(kt * 32 + quad * 8 + j) * 64 + n];
        }
    f16x8 wb2[2][4];
#pragma unroll
    for (int kt = 0; kt < 2; ++kt)
#pragma unroll
        for (int nf = 0; nf < 4; ++nf) {
            int n = nf * 16 + l15;
#pragma unroll
            for (int j = 0; j < 8; ++j)
                wb2[kt][nf][j] = (f16)We2[(kt * 32 + quad * 8 + j) * 64 + n];
        }

    float b1v[4], b2v[4];
#pragma unroll
    for (int nf = 0; nf < 4; ++nf) {
        b1v[nf] = be1[nf * 16 + l15];
        b2v[nf] = be2[nf * 16 + l15];
    }

    const int wid = blockIdx.x * 4 + w;   // global wave id
    const int nw  = gridDim.x * 4;

    // ---- pipeline prologue: tile0's x rows + tile1's edge indices ----
    int2 peC = eix[min(wid * 16 + l15, E - 1)];
    float4 s0, s1, s2, s3, d0v, d1v, d2v, d3v;
    {
        const float* ps = x + (size_t)peC.x * D;
        const float* pd = x + (size_t)peC.y * D;
        s0  = *(const float4*)(ps + quad * 8);
        s1  = *(const float4*)(ps + quad * 8 + 4);
        s2  = *(const float4*)(ps + 32 + quad * 8);
        s3  = *(const float4*)(ps + 32 + quad * 8 + 4);
        d0v = *(const float4*)(pd + quad * 8);
        d1v = *(const float4*)(pd + quad * 8 + 4);
        d2v = *(const float4*)(pd + 32 + quad * 8);
        d3v = *(const float4*)(pd + 32 + quad * 8 + 4);
    }
    int2 peN = eix[min((wid + nw) * 16 + l15, E - 1)];

    for (int tile = wid; tile < T; tile += nw) {
        const int e0 = tile * 16;

        int prevD = (e0 > 0)      ? eix[e0 - 1].y  : -2;   // wave-uniform
        int nextD = (e0 + 16 < E) ? eix[e0 + 16].y : -2;   // wave-uniform

        // ---- stage current tile (all from registers) ----
        *(float4*)&XC[l15 * 68 + quad * 8]          = s0;
        *(float4*)&XC[l15 * 68 + quad * 8 + 4]      = s1;
        *(float4*)&XC[l15 * 68 + 32 + quad * 8]     = s2;
        *(float4*)&XC[l15 * 68 + 32 + quad * 8 + 4] = s3;
        if (quad == 0) edst[l15] = (e0 + l15 < E) ? peC.y : N;

        f16x8 ah[4];
        ah[0][0]=(f16)s0.x; ah[0][1]=(f16)s0.y; ah[0][2]=(f16)s0.z; ah[0][3]=(f16)s0.w;
        ah[0][4]=(f16)s1.x; ah[0][5]=(f16)s1.y; ah[0][6]=(f16)s1.z; ah[0][7]=(f16)s1.w;
        ah[1][0]=(f16)s2.x; ah[1][1]=(f16)s2.y; ah[1][2]=(f16)s2.z; ah[1][3]=(f16)s2.w;
        ah[1][4]=(f16)s3.x; ah[1][5]=(f16)s3.y; ah[1][6]=(f16)s3.z; ah[1][7]=(f16)s3.w;
        ah[2][0]=(f16)d0v.x; ah[2][1]=(f16)d0v.y; ah[2][2]=(f16)d0v.z; ah[2][3]=(f16)d0v.w;
        ah[2][4]=(f16)d1v.x; ah[2][5]=(f16)d1v.y; ah[2][6]=(f16)d1v.z; ah[2][7]=(f16)d1v.w;
        ah[3][0]=(f16)d2v.x; ah[3][1]=(f16)d2v.y; ah[3][2]=(f16)d2v.z; ah[3][3]=(f16)d2v.w;
        ah[3][4]=(f16)d3v.x; ah[3][5]=(f16)d3v.y; ah[3][6]=(f16)d3v.z; ah[3][7]=(f16)d3v.w;

        // ---- prefetch: x rows for tile+nw, eix for tile+2nw ----
        float4 t0, t1, t2, t3, u0, u1, u2, u3;
        int2 peN2;
        {
            const float* ps2 = x + (size_t)peN.x * D;
            const float* pd2 = x + (size_t)peN.y * D;
            t0 = *(const float4*)(ps2 + quad * 8);
            t1 = *(const float4*)(ps2 + quad * 8 + 4);
            t2 = *(const float4*)(ps2 + 32 + quad * 8);
            t3 = *(const float4*)(ps2 + 32 + quad * 8 + 4);
            u0 = *(const float4*)(pd2 + quad * 8);
            u1 = *(const float4*)(pd2 + quad * 8 + 4);
            u2 = *(const float4*)(pd2 + 32 + quad * 8);
            u3 = *(const float4*)(pd2 + 32 + quad * 8 + 4);
            peN2 = eix[min((tile + 2 * nw) * 16 + l15, E - 1)];
        }

        // ---- GEMM1: [16,128]@[128,64] = 16 MFMA ----
        f32x4 acc[4] = {{0.f,0.f,0.f,0.f},{0.f,0.f,0.f,0.f},
                        {0.f,0.f,0.f,0.f},{0.f,0.f,0.f,0.f}};
#pragma unroll
        for (int kt = 0; kt < 4; ++kt)
#pragma unroll
            for (int nf = 0; nf < 4; ++nf)
                acc[nf] = __builtin_amdgcn_mfma_f32_16x16x32_f16(
                    ah[kt], wb1[kt][nf], acc[nf], 0, 0, 0);

        // ---- H = relu(acc+b1) -> Hbuf (ownership transpose) ----
#pragma unroll
        for (int nf = 0; nf < 4; ++nf)
#pragma unroll
            for (int i2 = 0; i2 < 4; ++i2)
                Hb[sw6(quad * 4 + i2, nf * 16 + l15)] =
                    (f16)fmaxf(acc[nf][i2] + b1v[nf], 0.f);

        // ---- GEMM2: [16,64]@[64,64] = 8 MFMA, A from Hbuf ----
        f32x4 dd[4] = {{0.f,0.f,0.f,0.f},{0.f,0.f,0.f,0.f},
                       {0.f,0.f,0.f,0.f},{0.f,0.f,0.f,0.f}};
#pragma unroll
        for (int kt = 0; kt < 2; ++kt) {
            f16x8 ah2 = *(const f16x8*)&Hb[sw6(l15, kt * 32 + quad * 8)];
#pragma unroll
            for (int nf = 0; nf < 4; ++nf)
                dd[nf] = __builtin_amdgcn_mfma_f32_16x16x32_f16(
                    ah2, wb2[kt][nf], dd[nf], 0, 0, 0);
        }

        // ---- contrib = xs * (d + b2), in-place in XC ----
#pragma unroll
        for (int nf = 0; nf < 4; ++nf)
#pragma unroll
            for (int i2 = 0; i2 < 4; ++i2) {
                int a = (quad * 4 + i2) * 68 + nf * 16 + l15;
                XC[a] = (dd[nf][i2] + b2v[nf]) * XC[a];
            }

        // ---- segmented sum over sorted dst runs (all 64 lanes = feature) ----
        {
            int j = lane;
            float a = 0.f;
            int cur = edst[0];
            int runStart = 0;
#pragma unroll
            for (int ii = 0; ii < 16; ++ii) {
                a += XC[ii * 68 + j];
                int nxt = (ii < 15) ? edst[ii + 1] : -3;
                if (nxt != cur) {
                    bool firstRun = (runStart == 0);
                    bool lastRun = (ii == 15) || (nxt >= N);
                    bool complete = (!firstRun || prevD != cur) &&
                                    (!lastRun || nextD != cur);
                    if (complete) hneigh[(size_t)cur * D + j] = a;
                    else atomicAdd(&hneigh[(size_t)cur * D + j], a);
                    a = 0.f; cur = nxt; runStart = ii + 1;
                }
            }
        }

        // ---- rotate pipeline registers ----
        s0 = t0; s1 = t1; s2 = t2; s3 = t3;
        d0v = u0; d1v = u1; d2v = u2; d3v = u3;
        peC = peN; peN = peN2;
        // NO barrier — stores retire asynchronously; next tile proceeds.
    }
}

// ---------------------------------------------------------------------------
// Node MLP via MFMA, weights in VGPR fragments, 2-term split.
// r19: grid = Tn exactly (one tile per block, no stride imbalance).
// ---------------------------------------------------------------------------
__global__ __launch_bounds__(256, 4) void node_mfma_kernel(
    float* __restrict__ h,
    const float* __restrict__ Wn, const float* __restrict__ bn,
    const float* __restrict__ Wg, const float* __restrict__ bg,
    float* __restrict__ gate, int N, int T)
{
    __shared__ __attribute__((aligned(16))) f16 ANhi[64 * 64];
    __shared__ __attribute__((aligned(16))) f16 ANlo[64 * 64];

    const int tid = threadIdx.x;
    const int w = tid >> 6;
    const int lane = tid & 63;
    const int l15 = lane & 15;
    const int quad = lane >> 4;
    const int m0 = w * 16;

    f16x8 wn[2][4];
#pragma unroll
    for (int kt = 0; kt < 2; ++kt)
#pragma unroll
        for (int nf = 0; nf < 4; ++nf) {
            int n = nf * 16 + l15;
#pragma unroll
            for (int j = 0; j < 8; ++j)
                wn[kt][nf][j] = (f16)Wn[(kt * 32 + quad * 8 + j) * 64 + n];
        }

    float bnv[4], wgv[4];
#pragma unroll
    for (int nt = 0; nt < 4; ++nt) {
        bnv[nt] = bn[nt * 16 + l15];
        wgv[nt] = Wg[nt * 16 + l15];
    }
    const float bgv = bg[0];

    for (int tile = blockIdx.x; tile < T; tile += gridDim.x) {
        const int t0 = tile * 64;

        {
            int i = tid >> 2;
            int q = tid & 3;
            int node = min(t0 + i, N - 1);
            const float* p = h + (size_t)node * D + q * 16;
#pragma unroll
            for (int r = 0; r < 4; ++r) {
                float4 v = *(const float4*)(p + r * 4);
                int k = q * 16 + r * 4;
                f16x4 hv, lv;
                hv[0] = (f16)v.x; lv[0] = (f16)(v.x - (float)hv[0]);
                hv[1] = (f16)v.y; lv[1] = (f16)(v.y - (float)hv[1]);
                hv[2] = (f16)v.z; lv[2] = (f16)(v.z - (float)hv[2]);
                hv[3] = (f16)v.w; lv[3] = (f16)(v.w - (float)hv[3]);
                *(f16x4*)&ANhi[sw6(i, k)] = hv;
                *(f16x4*)&ANlo[sw6(i, k)] = lv;
            }
        }
        __syncthreads();

        f32x4 cacc[4] = {{0.f,0.f,0.f,0.f},{0.f,0.f,0.f,0.f},{0.f,0.f,0.f,0.f},{0.f,0.f,0.f,0.f}};
#pragma unroll
        for (int kt = 0; kt < 2; ++kt) {
            int k = kt * 32 + quad * 8;
            f16x8 ah = *(const f16x8*)&ANhi[sw6(m0 + l15, k)];
            f16x8 al = *(const f16x8*)&ANlo[sw6(m0 + l15, k)];
#pragma unroll
            for (int nf = 0; nf < 4; ++nf) {
                cacc[nf] = __builtin_amdgcn_mfma_f32_16x16x32_f16(ah, wn[kt][nf], cacc[nf], 0, 0, 0);
                cacc[nf] = __builtin_amdgcn_mfma_f32_16x16x32_f16(al, wn[kt][nf], cacc[nf], 0, 0, 0);
            }
        }
        __syncthreads();

        float gpart[4] = {0.f, 0.f, 0.f, 0.f};
#pragma unroll
        for (int nt = 0; nt < 4; ++nt) {
            int n = nt * 16 + l15;
#pragma unroll
            for (int i2 = 0; i2 < 4; ++i2) {
                int m = t0 + m0 + quad * 4 + i2;
                float v = fmaxf(cacc[nt][i2] + bnv[nt], 0.f);
                if (m < N) h[(size_t)m * D + n] = v;
                gpart[i2] += v * wgv[nt];
            }
        }
#pragma unroll
        for (int s = 1; s < 16; s <<= 1) {
#pragma unroll
            for (int i2 = 0; i2 < 4; ++i2) gpart[i2] += __shfl_xor(gpart[i2], s);
        }
        if (l15 == 0) {
#pragma unroll
            for (int i2 = 0; i2 < 4; ++i2) {
                int m = t0 + m0 + quad * 4 + i2;
                if (m < N) gate[m] = gpart[i2] + bgv;
            }
        }
    }
}

// ---------------------------------------------------------------------------
// Pool SPLIT (r18 win; r19: PPARTS 4->8 => 1024 partial blocks, 4/CU).
// pool_partial computes LOCAL-max softmax partials (m_p, den_p, acc_p[64]);
// pool_combine rescales by exp(m_p - m) and applies the classifier.
// Exact up to fp reassociation. Partials overlay the dead eix2 region.
// ---------------------------------------------------------------------------
__global__ __launch_bounds__(256) void pool_partial(
    const float* __restrict__ h2,
    const float* __restrict__ gate,
    const int* __restrict__ gid,
    float* __restrict__ pm, float* __restrict__ pden,
    float* __restrict__ pacc, int N)
{
    int gb = blockIdx.x;
    int g = gb / PPARTS;
    int p = gb % PPARTS;
    int tid = threadIdx.x;

    int lo = 0, hi = N;
    while (lo < hi) { int mid = (lo + hi) >> 1; if (gid[mid] < g) lo = mid + 1; else hi = mid; }
    int s = lo;
    hi = N;
    while (lo < hi) { int mid = (lo + hi) >> 1; if (gid[mid] < g + 1) lo = mid + 1; else hi = mid; }
    int e = lo;

    int len = e - s;
    int st = s + (int)(((long long)len * p) / PPARTS);
    int en = s + (int)(((long long)len * (p + 1)) / PPARTS);

    __shared__ float red[256];
    __shared__ float accs[4][D];
    __shared__ float dens[4];

    // local max over this part
    float m = -INFINITY;
    for (int i = st + tid; i < en; i += 256) m = fmaxf(m, gate[i]);
    red[tid] = m;
    __syncthreads();
    for (int w = 128; w > 0; w >>= 1) {
        if (tid < w) red[tid] = fmaxf(red[tid], red[tid + w]);
        __syncthreads();
    }
    float lmax = red[0];
    __syncthreads();

    // weighted sums with local max
    int f = tid & (D - 1);
    int grp = tid >> 6;
    float acc = 0.0f, den = 0.0f;
    for (int i = st + grp; i < en; i += 4) {
        float wv = expf(gate[i] - lmax);
        acc += wv * h2[(size_t)i * D + f];
        if (f == 0) den += wv;
    }
    accs[grp][f] = acc;
    if (f == 0) dens[grp] = den;
    __syncthreads();

    if (tid < D)
        pacc[(size_t)gb * D + tid] =
            accs[0][tid] + accs[1][tid] + accs[2][tid] + accs[3][tid];
    if (tid == 0) {
        pden[gb] = dens[0] + dens[1] + dens[2] + dens[3];
        pm[gb] = lmax;
    }
}

__global__ __launch_bounds__(64) void pool_combine(
    const float* __restrict__ pm, const float* __restrict__ pden,
    const float* __restrict__ pacc,
    const float* __restrict__ Wfc, const float* __restrict__ bfc,
    float* __restrict__ out, int C)
{
    int g = blockIdx.x;
    int tid = threadIdx.x;   // 64 threads

    __shared__ float red[D];

    float m = -INFINITY;
#pragma unroll
    for (int p = 0; p < PPARTS; ++p) m = fmaxf(m, pm[g * PPARTS + p]);

    float den = 0.f, pf = 0.f;
#pragma unroll
    for (int p = 0; p < PPARTS; ++p) {
        float mp = pm[g * PPARTS + p];
        float sc = (mp > -INFINITY) ? expf(mp - m) : 0.f;
        den += pden[g * PPARTS + p] * sc;
        pf  += pacc[(size_t)(g * PPARTS + p) * D + tid] * sc;
    }
    red[tid] = (den > 0.f) ? (pf / den) : 0.f;
    __syncthreads();

    if (tid < C) {
        float o = bfc[tid];
#pragma unroll
        for (int k = 0; k < D; ++k) o += red[k] * Wfc[k * C + tid];
        out[g * C + tid] = o;
    }
}

extern "C" void kernel_launch(void* const* d_in, const int* in_sizes, int n_in,
                              void* d_out, int out_size, void* d_ws, size_t ws_size,
                              hipStream_t stream) {
    const float* x   = (const float*)d_in[0];
    const float* We1 = (const float*)d_in[1];
    const float* be1 = (const float*)d_in[2];
    const float* We2 = (const float*)d_in[3];
    const float* be2 = (const float*)d_in[4];
    const float* Wn  = (const float*)d_in[5];
    const float* bn  = (const float*)d_in[6];
    const float* Wg  = (const float*)d_in[7];
    const float* bg  = (const float*)d_in[8];
    const float* Wfc = (const float*)d_in[9];
    const float* bfc = (const float*)d_in[10];
    const int* src = (const int*)d_in[11];
    const int* dst = (const int*)d_in[12];
    const int* gid = (const int*)d_in[13];

    const int N = in_sizes[0] / D;
    const int E = in_sizes[11];
    const int C = 10;
    const int G = out_size / C;
    const int NB = (N + BNODES - 1) / BNODES;

    // workspace: eix2 | union{eixA, hneigh} | gate | bucket arrays
    // eix2 is dead after the edge kernel -> pool partials overlay it.
    int2*  eix2   = (int2*)d_ws;                          // [E]      12.8MB
    int2*  eixA   = eix2 + E;                             // [E]      12.8MB
    float* hneigh = (float*)eixA;                         // [(N+1)*64] 25.6MB (overlay)
    float* gate   = hneigh + (size_t)(N + 1) * D;         // [N]
    int*   bhist  = (int*)(gate + N);                     // [NB]
    int*   boff   = bhist + NB;                           // [NB+1]
    int*   bcursor= boff + NB + 1;                        // [NB]
    float* outp   = (float*)d_out;

    float* pm   = (float*)eix2;                           // [G*PPARTS] (overlay, post-edge)
    float* pden = pm + (size_t)G * PPARTS;                // [G*PPARTS]
    float* pacc = pden + (size_t)G * PPARTS;              // [G*PPARTS*D]

    const int Bh = (E + EB - 1) / EB;
    const int Te = (E + 15) / 16;     // 16-edge tiles, one wave each
    const int Tn = (N + 63) / 64;

    hipMemsetAsync(bhist, 0, (size_t)NB * sizeof(int), stream);

    bucket_hist<<<Bh, 256, 0, stream>>>(dst, bhist, E, NB);
    bucket_scan<<<1, 256, 0, stream>>>(bhist, boff, bcursor, NB);
    bucket_fill<<<Bh, 256, 0, stream>>>(dst, src, bcursor, eixA, E, NB);
    bucket_sort<<<NB, 256, 0, stream>>>(eixA, boff, eix2, NB);

    // eixA dead; zero hneigh (overlay) before edge kernel
    hipMemsetAsync(hneigh, 0, (size_t)(N + 1) * D * sizeof(float), stream);

    edge_mfma_kernel<<<512, 256, 0, stream>>>(x, We1, be1, We2, be2,
                                              eix2, hneigh, N, E, Te);
    node_mfma_kernel<<<Tn, 256, 0, stream>>>(hneigh, Wn, bn, Wg, bg, gate, N, Tn);
    pool_partial<<<G * PPARTS, 256, 0, stream>>>(hneigh, gate, gid,
                                                 pm, pden, pacc, N);
    pool_combine<<<G, 64, 0, stream>>>(pm, pden, pacc, Wfc, bfc, outp, C);
}

// Round 20
// 334.692 us; speedup vs baseline: 1.3733x; 1.0314x over previous
//
#include <hip/hip_runtime.h>
#include <hip/hip_bf16.h>

#define D 64
#define BSH 6            // log2(nodes per bucket)
#define BNODES 64
#define NBMAX 2048       // LDS hist capacity (N <= 131072)
#define EB 8192          // edges per hist/fill block (r20: 4096->8192)
#define PPARTS 16        // pool partial blocks per graph (r20: 8->16)

typedef _Float16 f16;
typedef _Float16 f16x4 __attribute__((ext_vector_type(4)));
typedef _Float16 f16x8 __attribute__((ext_vector_type(8)));
typedef float f32x4 __attribute__((ext_vector_type(4)));

__device__ __forceinline__ int sw6(int m, int k) {  // row stride 64 f16
    return (m << 6) + ((((k >> 3) ^ (m & 7)) & 7) << 3) + (k & 7);
}

// ---------------------------------------------------------------------------
// Bucket partition (coarse sort by dst>>6) — two-level LDS histograms.
// r20: EB doubled -> half the blocks -> half the global-atomic flush rounds.
// ---------------------------------------------------------------------------
__global__ __launch_bounds__(256) void bucket_hist(
    const int* __restrict__ dst, int* __restrict__ bhist, int E, int NB)
{
    __shared__ int lhist[NBMAX];
    int tid = threadIdx.x;
    for (int b = tid; b < NB; b += 256) lhist[b] = 0;
    __syncthreads();
    int base = blockIdx.x * EB;
#pragma unroll
    for (int r = 0; r < EB / 256; ++r) {
        int e = base + r * 256 + tid;
        if (e < E) atomicAdd(&lhist[dst[e] >> BSH], 1);
    }
    __syncthreads();
    for (int b = tid; b < NB; b += 256) {
        int v = lhist[b];
        if (v) atomicAdd(&bhist[b], v);
    }
}

__global__ __launch_bounds__(256) void bucket_scan(
    const int* __restrict__ bhist, int* __restrict__ boff,
    int* __restrict__ bcursor, int NB)
{
    __shared__ int lds[256];
    int tid = threadIdx.x;
    int chunk = (NB + 255) / 256;
    int b0 = tid * chunk;
    int b1 = min(b0 + chunk, NB);
    int s = 0;
    for (int b = b0; b < b1; ++b) s += bhist[b];
    lds[tid] = s;
    __syncthreads();
    for (int d2 = 1; d2 < 256; d2 <<= 1) {
        int v = (tid >= d2) ? lds[tid - d2] : 0;
        __syncthreads();
        lds[tid] += v;
        __syncthreads();
    }
    int run = (tid == 0) ? 0 : lds[tid - 1];
    for (int b = b0; b < b1; ++b) {
        boff[b] = run;
        bcursor[b] = run;
        run += bhist[b];
    }
    if (tid == 255) boff[NB] = lds[255];
}

__global__ __launch_bounds__(256) void bucket_fill(
    const int* __restrict__ dst, const int* __restrict__ src,
    int* __restrict__ bcursor, int2* __restrict__ eix, int E, int NB)
{
    __shared__ int lhist[NBMAX];
    __shared__ int lcur[NBMAX];
    int tid = threadIdx.x;
    for (int b = tid; b < NB; b += 256) lhist[b] = 0;
    __syncthreads();
    int base = blockIdx.x * EB;
    int dv[EB / 256];
#pragma unroll
    for (int r = 0; r < EB / 256; ++r) {
        int e = base + r * 256 + tid;
        dv[r] = (e < E) ? dst[e] : -1;
        if (dv[r] >= 0) atomicAdd(&lhist[dv[r] >> BSH], 1);
    }
    __syncthreads();
    for (int b = tid; b < NB; b += 256) {
        int v = lhist[b];
        lcur[b] = v ? atomicAdd(&bcursor[b], v) : 0;
    }
    __syncthreads();
#pragma unroll
    for (int r = 0; r < EB / 256; ++r) {
        int e = base + r * 256 + tid;
        if (dv[r] >= 0) {
            int p = atomicAdd(&lcur[dv[r] >> BSH], 1);
            eix[p] = make_int2(src[e], dv[r]);
        }
    }
}

// ---------------------------------------------------------------------------
// Per-bucket exact counting sort (64 bins in LDS) -> globally dst-sorted eix2.
// ---------------------------------------------------------------------------
__global__ __launch_bounds__(256) void bucket_sort(
    const int2* __restrict__ eix, const int* __restrict__ boff,
    int2* __restrict__ eix2, int NB)
{
    __shared__ int h64[BNODES];
    __shared__ int cur64[BNODES];
    int bk = blockIdx.x;
    int s = boff[bk], e = boff[bk + 1];
    int tid = threadIdx.x;
    int nbase = bk << BSH;

    if (tid < BNODES) h64[tid] = 0;
    __syncthreads();
    for (int i = s + tid; i < e; i += 256)
        atomicAdd(&h64[eix[i].y - nbase], 1);
    __syncthreads();
    if (tid < BNODES) {
        int v = h64[tid];
        int inc = v;
        for (int d2 = 1; d2 < BNODES; d2 <<= 1) {   // wave-level inclusive scan
            int t = __shfl_up(inc, d2);
            if (tid >= d2) inc += t;
        }
        cur64[tid] = inc - v;                        // exclusive prefix
    }
    __syncthreads();
    for (int i = s + tid; i < e; i += 256) {
        int2 ed = eix[i];
        int slot = atomicAdd(&cur64[ed.y - nbase], 1);
        eix2[s + slot] = ed;
    }
}

// ---------------------------------------------------------------------------
// Edge MLP via MFMA — barrier-free wave-independent tiles + register pipeline
// (r10 structure, best measured: 143.9-145.7us, bank conflicts 0, VGPR 108).
//
// Ledger: r0 192 lockstep; r1/r9 forced-occ SPILL; r5 occ-lockstep dead;
// r6 prefetch-lockstep neutral; r8 barrier-free 154; r10 reg-pipeline 144.5;
// r14 2-way ILP neutral (LDS-instruction-stream bound); r17 coop REGRESSED;
// r18 pool-split WIN; r19 PPARTS8+node-grid WIN (345.2). Edge untouched.
// ---------------------------------------------------------------------------
__global__ __launch_bounds__(256, 2) void edge_mfma_kernel(
    const float* __restrict__ x,
    const float* __restrict__ We1, const float* __restrict__ be1,
    const float* __restrict__ We2, const float* __restrict__ be2,
    const int2* __restrict__ eix,
    float* __restrict__ hneigh, int N, int E, int T)
{
    __shared__ __attribute__((aligned(16))) float XCs[4][16 * 68];  // 17.4KB
    __shared__ __attribute__((aligned(16))) f16   Hbs[4][16 * 64];  // 8KB
    __shared__ int edsts[4][16];                                    // 256B

    const int tid  = threadIdx.x;
    const int w    = tid >> 6;
    const int lane = tid & 63;
    const int l15  = lane & 15;
    const int quad = lane >> 4;

    float* XC  = XCs[w];
    f16*   Hb  = Hbs[w];
    int*   edst = edsts[w];

    // Full weight sets in registers: wb1 (64 VGPR), wb2 (32 VGPR).
    f16x8 wb1[4][4];
#pragma unroll
    for (int kt = 0; kt < 4; ++kt)
#pragma unroll
        for (int nf = 0; nf < 4; ++nf) {
            int n = nf * 16 + l15;
#pragma unroll
            for (int j = 0; j < 8; ++j)
                wb1[kt][nf][j] = (f16)We1[(kt * 32 + quad * 8 + j) * 64 + n];
        }
    f16x8 wb2[2][4];
#pragma unroll
    for (int kt = 0; kt < 2; ++kt)
#pragma unroll
        for (int nf = 0; nf < 4; ++nf) {
            int n = nf * 16 + l15;
#pragma unroll
            for (int j = 0; j < 8; ++j)
                wb2[kt][nf][j] = (f16)We2[(kt * 32 + quad * 8 + j) * 64 + n];
        }

    float b1v[4], b2v[4];
#pragma unroll
    for (int nf = 0; nf < 4; ++nf) {
        b1v[nf] = be1[nf * 16 + l15];
        b2v[nf] = be2[nf * 16 + l15];
    }

    const int wid = blockIdx.x * 4 + w;   // global wave id
    const int nw  = gridDim.x * 4;

    // ---- pipeline prologue: tile0's x rows + tile1's edge indices ----
    int2 peC = eix[min(wid * 16 + l15, E - 1)];
    float4 s0, s1, s2, s3, d0v, d1v, d2v, d3v;
    {
        const float* ps = x + (size_t)peC.x * D;
        const float* pd = x + (size_t)peC.y * D;
        s0  = *(const float4*)(ps + quad * 8);
        s1  = *(const float4*)(ps + quad * 8 + 4);
        s2  = *(const float4*)(ps + 32 + quad * 8);
        s3  = *(const float4*)(ps + 32 + quad * 8 + 4);
        d0v = *(const float4*)(pd + quad * 8);
        d1v = *(const float4*)(pd + quad * 8 + 4);
        d2v = *(const float4*)(pd + 32 + quad * 8);
        d3v = *(const float4*)(pd + 32 + quad * 8 + 4);
    }
    int2 peN = eix[min((wid + nw) * 16 + l15, E - 1)];

    for (int tile = wid; tile < T; tile += nw) {
        const int e0 = tile * 16;

        int prevD = (e0 > 0)      ? eix[e0 - 1].y  : -2;   // wave-uniform
        int nextD = (e0 + 16 < E) ? eix[e0 + 16].y : -2;   // wave-uniform

        // ---- stage current tile (all from registers) ----
        *(float4*)&XC[l15 * 68 + quad * 8]          = s0;
        *(float4*)&XC[l15 * 68 + quad * 8 + 4]      = s1;
        *(float4*)&XC[l15 * 68 + 32 + quad * 8]     = s2;
        *(float4*)&XC[l15 * 68 + 32 + quad * 8 + 4] = s3;
        if (quad == 0) edst[l15] = (e0 + l15 < E) ? peC.y : N;

        f16x8 ah[4];
        ah[0][0]=(f16)s0.x; ah[0][1]=(f16)s0.y; ah[0][2]=(f16)s0.z; ah[0][3]=(f16)s0.w;
        ah[0][4]=(f16)s1.x; ah[0][5]=(f16)s1.y; ah[0][6]=(f16)s1.z; ah[0][7]=(f16)s1.w;
        ah[1][0]=(f16)s2.x; ah[1][1]=(f16)s2.y; ah[1][2]=(f16)s2.z; ah[1][3]=(f16)s2.w;
        ah[1][4]=(f16)s3.x; ah[1][5]=(f16)s3.y; ah[1][6]=(f16)s3.z; ah[1][7]=(f16)s3.w;
        ah[2][0]=(f16)d0v.x; ah[2][1]=(f16)d0v.y; ah[2][2]=(f16)d0v.z; ah[2][3]=(f16)d0v.w;
        ah[2][4]=(f16)d1v.x; ah[2][5]=(f16)d1v.y; ah[2][6]=(f16)d1v.z; ah[2][7]=(f16)d1v.w;
        ah[3][0]=(f16)d2v.x; ah[3][1]=(f16)d2v.y; ah[3][2]=(f16)d2v.z; ah[3][3]=(f16)d2v.w;
        ah[3][4]=(f16)d3v.x; ah[3][5]=(f16)d3v.y; ah[3][6]=(f16)d3v.z; ah[3][7]=(f16)d3v.w;

        // ---- prefetch: x rows for tile+nw, eix for tile+2nw ----
        float4 t0, t1, t2, t3, u0, u1, u2, u3;
        int2 peN2;
        {
            const float* ps2 = x + (size_t)peN.x * D;
            const float* pd2 = x + (size_t)peN.y * D;
            t0 = *(const float4*)(ps2 + quad * 8);
            t1 = *(const float4*)(ps2 + quad * 8 + 4);
            t2 = *(const float4*)(ps2 + 32 + quad * 8);
            t3 = *(const float4*)(ps2 + 32 + quad * 8 + 4);
            u0 = *(const float4*)(pd2 + quad * 8);
            u1 = *(const float4*)(pd2 + quad * 8 + 4);
            u2 = *(const float4*)(pd2 + 32 + quad * 8);
            u3 = *(const float4*)(pd2 + 32 + quad * 8 + 4);
            peN2 = eix[min((tile + 2 * nw) * 16 + l15, E - 1)];
        }

        // ---- GEMM1: [16,128]@[128,64] = 16 MFMA ----
        f32x4 acc[4] = {{0.f,0.f,0.f,0.f},{0.f,0.f,0.f,0.f},
                        {0.f,0.f,0.f,0.f},{0.f,0.f,0.f,0.f}};
#pragma unroll
        for (int kt = 0; kt < 4; ++kt)
#pragma unroll
            for (int nf = 0; nf < 4; ++nf)
                acc[nf] = __builtin_amdgcn_mfma_f32_16x16x32_f16(
                    ah[kt], wb1[kt][nf], acc[nf], 0, 0, 0);

        // ---- H = relu(acc+b1) -> Hbuf (ownership transpose) ----
#pragma unroll
        for (int nf = 0; nf < 4; ++nf)
#pragma unroll
            for (int i2 = 0; i2 < 4; ++i2)
                Hb[sw6(quad * 4 + i2, nf * 16 + l15)] =
                    (f16)fmaxf(acc[nf][i2] + b1v[nf], 0.f);

        // ---- GEMM2: [16,64]@[64,64] = 8 MFMA, A from Hbuf ----
        f32x4 dd[4] = {{0.f,0.f,0.f,0.f},{0.f,0.f,0.f,0.f},
                       {0.f,0.f,0.f,0.f},{0.f,0.f,0.f,0.f}};
#pragma unroll
        for (int kt = 0; kt < 2; ++kt) {
            f16x8 ah2 = *(const f16x8*)&Hb[sw6(l15, kt * 32 + quad * 8)];
#pragma unroll
            for (int nf = 0; nf < 4; ++nf)
                dd[nf] = __builtin_amdgcn_mfma_f32_16x16x32_f16(
                    ah2, wb2[kt][nf], dd[nf], 0, 0, 0);
        }

        // ---- contrib = xs * (d + b2), in-place in XC ----
#pragma unroll
        for (int nf = 0; nf < 4; ++nf)
#pragma unroll
            for (int i2 = 0; i2 < 4; ++i2) {
                int a = (quad * 4 + i2) * 68 + nf * 16 + l15;
                XC[a] = (dd[nf][i2] + b2v[nf]) * XC[a];
            }

        // ---- segmented sum over sorted dst runs (all 64 lanes = feature) ----
        {
            int j = lane;
            float a = 0.f;
            int cur = edst[0];
            int runStart = 0;
#pragma unroll
            for (int ii = 0; ii < 16; ++ii) {
                a += XC[ii * 68 + j];
                int nxt = (ii < 15) ? edst[ii + 1] : -3;
                if (nxt != cur) {
                    bool firstRun = (runStart == 0);
                    bool lastRun = (ii == 15) || (nxt >= N);
                    bool complete = (!firstRun || prevD != cur) &&
                                    (!lastRun || nextD != cur);
                    if (complete) hneigh[(size_t)cur * D + j] = a;
                    else atomicAdd(&hneigh[(size_t)cur * D + j], a);
                    a = 0.f; cur = nxt; runStart = ii + 1;
                }
            }
        }

        // ---- rotate pipeline registers ----
        s0 = t0; s1 = t1; s2 = t2; s3 = t3;
        d0v = u0; d1v = u1; d2v = u2; d3v = u3;
        peC = peN; peN = peN2;
        // NO barrier — stores retire asynchronously; next tile proceeds.
    }
}

// ---------------------------------------------------------------------------
// Node MLP via MFMA, weights in VGPR fragments, 2-term split.
// Grid = Tn exactly (one tile per block).
// ---------------------------------------------------------------------------
__global__ __launch_bounds__(256, 4) void node_mfma_kernel(
    float* __restrict__ h,
    const float* __restrict__ Wn, const float* __restrict__ bn,
    const float* __restrict__ Wg, const float* __restrict__ bg,
    float* __restrict__ gate, int N, int T)
{
    __shared__ __attribute__((aligned(16))) f16 ANhi[64 * 64];
    __shared__ __attribute__((aligned(16))) f16 ANlo[64 * 64];

    const int tid = threadIdx.x;
    const int w = tid >> 6;
    const int lane = tid & 63;
    const int l15 = lane & 15;
    const int quad = lane >> 4;
    const int m0 = w * 16;

    f16x8 wn[2][4];
#pragma unroll
    for (int kt = 0; kt < 2; ++kt)
#pragma unroll
        for (int nf = 0; nf < 4; ++nf) {
            int n = nf * 16 + l15;
#pragma unroll
            for (int j = 0; j < 8; ++j)
                wn[kt][nf][j] = (f16)Wn[(kt * 32 + quad * 8 + j) * 64 + n];
        }

    float bnv[4], wgv[4];
#pragma unroll
    for (int nt = 0; nt < 4; ++nt) {
        bnv[nt] = bn[nt * 16 + l15];
        wgv[nt] = Wg[nt * 16 + l15];
    }
    const float bgv = bg[0];

    for (int tile = blockIdx.x; tile < T; tile += gridDim.x) {
        const int t0 = tile * 64;

        {
            int i = tid >> 2;
            int q = tid & 3;
            int node = min(t0 + i, N - 1);
            const float* p = h + (size_t)node * D + q * 16;
#pragma unroll
            for (int r = 0; r < 4; ++r) {
                float4 v = *(const float4*)(p + r * 4);
                int k = q * 16 + r * 4;
                f16x4 hv, lv;
                hv[0] = (f16)v.x; lv[0] = (f16)(v.x - (float)hv[0]);
                hv[1] = (f16)v.y; lv[1] = (f16)(v.y - (float)hv[1]);
                hv[2] = (f16)v.z; lv[2] = (f16)(v.z - (float)hv[2]);
                hv[3] = (f16)v.w; lv[3] = (f16)(v.w - (float)hv[3]);
                *(f16x4*)&ANhi[sw6(i, k)] = hv;
                *(f16x4*)&ANlo[sw6(i, k)] = lv;
            }
        }
        __syncthreads();

        f32x4 cacc[4] = {{0.f,0.f,0.f,0.f},{0.f,0.f,0.f,0.f},{0.f,0.f,0.f,0.f},{0.f,0.f,0.f,0.f}};
#pragma unroll
        for (int kt = 0; kt < 2; ++kt) {
            int k = kt * 32 + quad * 8;
            f16x8 ah = *(const f16x8*)&ANhi[sw6(m0 + l15, k)];
            f16x8 al = *(const f16x8*)&ANlo[sw6(m0 + l15, k)];
#pragma unroll
            for (int nf = 0; nf < 4; ++nf) {
                cacc[nf] = __builtin_amdgcn_mfma_f32_16x16x32_f16(ah, wn[kt][nf], cacc[nf], 0, 0, 0);
                cacc[nf] = __builtin_amdgcn_mfma_f32_16x16x32_f16(al, wn[kt][nf], cacc[nf], 0, 0, 0);
            }
        }
        __syncthreads();

        float gpart[4] = {0.f, 0.f, 0.f, 0.f};
#pragma unroll
        for (int nt = 0; nt < 4; ++nt) {
            int n = nt * 16 + l15;
#pragma unroll
            for (int i2 = 0; i2 < 4; ++i2) {
                int m = t0 + m0 + quad * 4 + i2;
                float v = fmaxf(cacc[nt][i2] + bnv[nt], 0.f);
                if (m < N) h[(size_t)m * D + n] = v;
                gpart[i2] += v * wgv[nt];
            }
        }
#pragma unroll
        for (int s = 1; s < 16; s <<= 1) {
#pragma unroll
            for (int i2 = 0; i2 < 4; ++i2) gpart[i2] += __shfl_xor(gpart[i2], s);
        }
        if (l15 == 0) {
#pragma unroll
            for (int i2 = 0; i2 < 4; ++i2) {
                int m = t0 + m0 + quad * 4 + i2;
                if (m < N) gate[m] = gpart[i2] + bgv;
            }
        }
    }
}

// ---------------------------------------------------------------------------
// Pool SPLIT (r18/r19 wins; r20: PPARTS 8->16 => 2048 partial blocks, 8/CU).
// pool_partial computes LOCAL-max softmax partials (m_p, den_p, acc_p[64]);
// pool_combine rescales by exp(m_p - m) and applies the classifier.
// Exact up to fp reassociation. Partials overlay the dead eix2 region.
// ---------------------------------------------------------------------------
__global__ __launch_bounds__(256) void pool_partial(
    const float* __restrict__ h2,
    const float* __restrict__ gate,
    const int* __restrict__ gid,
    float* __restrict__ pm, float* __restrict__ pden,
    float* __restrict__ pacc, int N)
{
    int gb = blockIdx.x;
    int g = gb / PPARTS;
    int p = gb % PPARTS;
    int tid = threadIdx.x;

    int lo = 0, hi = N;
    while (lo < hi) { int mid = (lo + hi) >> 1; if (gid[mid] < g) lo = mid + 1; else hi = mid; }
    int s = lo;
    hi = N;
    while (lo < hi) { int mid = (lo + hi) >> 1; if (gid[mid] < g + 1) lo = mid + 1; else hi = mid; }
    int e = lo;

    int len = e - s;
    int st = s + (int)(((long long)len * p) / PPARTS);
    int en = s + (int)(((long long)len * (p + 1)) / PPARTS);

    __shared__ float red[256];
    __shared__ float accs[4][D];
    __shared__ float dens[4];

    // local max over this part
    float m = -INFINITY;
    for (int i = st + tid; i < en; i += 256) m = fmaxf(m, gate[i]);
    red[tid] = m;
    __syncthreads();
    for (int w = 128; w > 0; w >>= 1) {
        if (tid < w) red[tid] = fmaxf(red[tid], red[tid + w]);
        __syncthreads();
    }
    float lmax = red[0];
    __syncthreads();

    // weighted sums with local max
    int f = tid & (D - 1);
    int grp = tid >> 6;
    float acc = 0.0f, den = 0.0f;
    for (int i = st + grp; i < en; i += 4) {
        float wv = expf(gate[i] - lmax);
        acc += wv * h2[(size_t)i * D + f];
        if (f == 0) den += wv;
    }
    accs[grp][f] = acc;
    if (f == 0) dens[grp] = den;
    __syncthreads();

    if (tid < D)
        pacc[(size_t)gb * D + tid] =
            accs[0][tid] + accs[1][tid] + accs[2][tid] + accs[3][tid];
    if (tid == 0) {
        pden[gb] = dens[0] + dens[1] + dens[2] + dens[3];
        pm[gb] = lmax;
    }
}

__global__ __launch_bounds__(64) void pool_combine(
    const float* __restrict__ pm, const float* __restrict__ pden,
    const float* __restrict__ pacc,
    const float* __restrict__ Wfc, const float* __restrict__ bfc,
    float* __restrict__ out, int C)
{
    int g = blockIdx.x;
    int tid = threadIdx.x;   // 64 threads

    __shared__ float red[D];

    float m = -INFINITY;
#pragma unroll
    for (int p = 0; p < PPARTS; ++p) m = fmaxf(m, pm[g * PPARTS + p]);

    float den = 0.f, pf = 0.f;
#pragma unroll
    for (int p = 0; p < PPARTS; ++p) {
        float mp = pm[g * PPARTS + p];
        float sc = (mp > -INFINITY) ? expf(mp - m) : 0.f;
        den += pden[g * PPARTS + p] * sc;
        pf  += pacc[(size_t)(g * PPARTS + p) * D + tid] * sc;
    }
    red[tid] = (den > 0.f) ? (pf / den) : 0.f;
    __syncthreads();

    if (tid < C) {
        float o = bfc[tid];
#pragma unroll
        for (int k = 0; k < D; ++k) o += red[k] * Wfc[k * C + tid];
        out[g * C + tid] = o;
    }
}

extern "C" void kernel_launch(void* const* d_in, const int* in_sizes, int n_in,
                              void* d_out, int out_size, void* d_ws, size_t ws_size,
                              hipStream_t stream) {
    const float* x   = (const float*)d_in[0];
    const float* We1 = (const float*)d_in[1];
    const float* be1 = (const float*)d_in[2];
    const float* We2 = (const float*)d_in[3];
    const float* be2 = (const float*)d_in[4];
    const float* Wn  = (const float*)d_in[5];
    const float* bn  = (const float*)d_in[6];
    const float* Wg  = (const float*)d_in[7];
    const float* bg  = (const float*)d_in[8];
    const float* Wfc = (const float*)d_in[9];
    const float* bfc = (const float*)d_in[10];
    const int* src = (const int*)d_in[11];
    const int* dst = (const int*)d_in[12];
    const int* gid = (const int*)d_in[13];

    const int N = in_sizes[0] / D;
    const int E = in_sizes[11];
    const int C = 10;
    const int G = out_size / C;
    const int NB = (N + BNODES - 1) / BNODES;

    // workspace: eix2 | union{eixA, hneigh} | gate | bucket arrays
    // eix2 is dead after the edge kernel -> pool partials overlay it.
    int2*  eix2   = (int2*)d_ws;                          // [E]      12.8MB
    int2*  eixA   = eix2 + E;                             // [E]      12.8MB
    float* hneigh = (float*)eixA;                         // [(N+1)*64] 25.6MB (overlay)
    float* gate   = hneigh + (size_t)(N + 1) * D;         // [N]
    int*   bhist  = (int*)(gate + N);                     // [NB]
    int*   boff   = bhist + NB;                           // [NB+1]
    int*   bcursor= boff + NB + 1;                        // [NB]
    float* outp   = (float*)d_out;

    float* pm   = (float*)eix2;                           // [G*PPARTS] (overlay, post-edge)
    float* pden = pm + (size_t)G * PPARTS;                // [G*PPARTS]
    float* pacc = pden + (size_t)G * PPARTS;              // [G*PPARTS*D]

    const int Bh = (E + EB - 1) / EB;
    const int Te = (E + 15) / 16;     // 16-edge tiles, one wave each
    const int Tn = (N + 63) / 64;

    hipMemsetAsync(bhist, 0, (size_t)NB * sizeof(int), stream);

    bucket_hist<<<Bh, 256, 0, stream>>>(dst, bhist, E, NB);
    bucket_scan<<<1, 256, 0, stream>>>(bhist, boff, bcursor, NB);
    bucket_fill<<<Bh, 256, 0, stream>>>(dst, src, bcursor, eixA, E, NB);
    bucket_sort<<<NB, 256, 0, stream>>>(eixA, boff, eix2, NB);

    // eixA dead; zero hneigh (overlay) before edge kernel
    hipMemsetAsync(hneigh, 0, (size_t)(N + 1) * D * sizeof(float), stream);

    edge_mfma_kernel<<<512, 256, 0, stream>>>(x, We1, be1, We2, be2,
                                              eix2, hneigh, N, E, Te);
    node_mfma_kernel<<<Tn, 256, 0, stream>>>(hneigh, Wn, bn, Wg, bg, gate, N, Tn);
    pool_partial<<<G * PPARTS, 256, 0, stream>>>(hneigh, gate, gid,
                                                 pm, pden, pacc, N);
    pool_combine<<<G, 64, 0, stream>>>(pm, pden, pacc, Wfc, bfc, outp, C);
}

// Round 22
// 333.722 us; speedup vs baseline: 1.3773x; 1.0029x over previous
//
#include <hip/hip_runtime.h>
#include <hip/hip_bf16.h>

#define D 64
#define BSH 6            // log2(nodes per bucket)
#define BNODES 64
#define NBMAX 2048       // LDS hist capacity (N <= 131072)
#define EB 8192          // edges per hist/fill block
#define PPARTS 16        // pool partial blocks per graph

typedef _Float16 f16;
typedef _Float16 f16x4 __attribute__((ext_vector_type(4)));
typedef _Float16 f16x8 __attribute__((ext_vector_type(8)));
typedef float f32x4 __attribute__((ext_vector_type(4)));

__device__ __forceinline__ int sw6(int m, int k) {  // row stride 64 f16
    return (m << 6) + ((((k >> 3) ^ (m & 7)) & 7) << 3) + (k & 7);
}

// ---------------------------------------------------------------------------
// Bucket partition (coarse sort by dst>>6) — two-level LDS histograms.
// r21 LESSON: hneigh OVERLAYS eixA — zeroing hneigh concurrently with the
// sort (which reads eixA) is an aliasing race (crashed). The memset must
// stay stream-ordered after bucket_sort. Reverted to r20 (best: 334.7us).
// ---------------------------------------------------------------------------
__global__ __launch_bounds__(256) void bucket_hist(
    const int* __restrict__ dst, int* __restrict__ bhist, int E, int NB)
{
    __shared__ int lhist[NBMAX];
    int tid = threadIdx.x;
    for (int b = tid; b < NB; b += 256) lhist[b] = 0;
    __syncthreads();
    int base = blockIdx.x * EB;
#pragma unroll
    for (int r = 0; r < EB / 256; ++r) {
        int e = base + r * 256 + tid;
        if (e < E) atomicAdd(&lhist[dst[e] >> BSH], 1);
    }
    __syncthreads();
    for (int b = tid; b < NB; b += 256) {
        int v = lhist[b];
        if (v) atomicAdd(&bhist[b], v);
    }
}

__global__ __launch_bounds__(256) void bucket_scan(
    const int* __restrict__ bhist, int* __restrict__ boff,
    int* __restrict__ bcursor, int NB)
{
    __shared__ int lds[256];
    int tid = threadIdx.x;
    int chunk = (NB + 255) / 256;
    int b0 = tid * chunk;
    int b1 = min(b0 + chunk, NB);
    int s = 0;
    for (int b = b0; b < b1; ++b) s += bhist[b];
    lds[tid] = s;
    __syncthreads();
    for (int d2 = 1; d2 < 256; d2 <<= 1) {
        int v = (tid >= d2) ? lds[tid - d2] : 0;
        __syncthreads();
        lds[tid] += v;
        __syncthreads();
    }
    int run = (tid == 0) ? 0 : lds[tid - 1];
    for (int b = b0; b < b1; ++b) {
        boff[b] = run;
        bcursor[b] = run;
        run += bhist[b];
    }
    if (tid == 255) boff[NB] = lds[255];
}

__global__ __launch_bounds__(256) void bucket_fill(
    const int* __restrict__ dst, const int* __restrict__ src,
    int* __restrict__ bcursor, int2* __restrict__ eix, int E, int NB)
{
    __shared__ int lhist[NBMAX];
    __shared__ int lcur[NBMAX];
    int tid = threadIdx.x;
    for (int b = tid; b < NB; b += 256) lhist[b] = 0;
    __syncthreads();
    int base = blockIdx.x * EB;
    int dv[EB / 256];
#pragma unroll
    for (int r = 0; r < EB / 256; ++r) {
        int e = base + r * 256 + tid;
        dv[r] = (e < E) ? dst[e] : -1;
        if (dv[r] >= 0) atomicAdd(&lhist[dv[r] >> BSH], 1);
    }
    __syncthreads();
    for (int b = tid; b < NB; b += 256) {
        int v = lhist[b];
        lcur[b] = v ? atomicAdd(&bcursor[b], v) : 0;
    }
    __syncthreads();
#pragma unroll
    for (int r = 0; r < EB / 256; ++r) {
        int e = base + r * 256 + tid;
        if (dv[r] >= 0) {
            int p = atomicAdd(&lcur[dv[r] >> BSH], 1);
            eix[p] = make_int2(src[e], dv[r]);
        }
    }
}

// ---------------------------------------------------------------------------
// Per-bucket exact counting sort (64 bins in LDS) -> globally dst-sorted eix2.
// ---------------------------------------------------------------------------
__global__ __launch_bounds__(256) void bucket_sort(
    const int2* __restrict__ eix, const int* __restrict__ boff,
    int2* __restrict__ eix2, int NB)
{
    __shared__ int h64[BNODES];
    __shared__ int cur64[BNODES];
    int bk = blockIdx.x;
    int s = boff[bk], e = boff[bk + 1];
    int tid = threadIdx.x;
    int nbase = bk << BSH;

    if (tid < BNODES) h64[tid] = 0;
    __syncthreads();
    for (int i = s + tid; i < e; i += 256)
        atomicAdd(&h64[eix[i].y - nbase], 1);
    __syncthreads();
    if (tid < BNODES) {
        int v = h64[tid];
        int inc = v;
        for (int d2 = 1; d2 < BNODES; d2 <<= 1) {   // wave-level inclusive scan
            int t = __shfl_up(inc, d2);
            if (tid >= d2) inc += t;
        }
        cur64[tid] = inc - v;                        // exclusive prefix
    }
    __syncthreads();
    for (int i = s + tid; i < e; i += 256) {
        int2 ed = eix[i];
        int slot = atomicAdd(&cur64[ed.y - nbase], 1);
        eix2[s + slot] = ed;
    }
}

// ---------------------------------------------------------------------------
// Edge MLP via MFMA — barrier-free wave-independent tiles + register pipeline
// (r10 structure, best measured: 143.9-146.8us, bank conflicts 0, VGPR 108).
//
// Ledger: r0 192 lockstep; r1/r9 forced-occ SPILL; r5 occ-lockstep dead;
// r6 prefetch-lockstep neutral; r8 barrier-free 154; r10 reg-pipeline 144.5;
// r14 2-way ILP neutral (LDS-instruction-stream bound); r17 coop REGRESSED;
// r18 pool-split WIN; r19 PPARTS8+node-grid WIN; r20 EB8192+PPARTS16 WIN
// (334.7); r21 concurrent-zero REFUTED (hneigh/eixA aliasing race).
// ---------------------------------------------------------------------------
__global__ __launch_bounds__(256, 2) void edge_mfma_kernel(
    const float* __restrict__ x,
    const float* __restrict__ We1, const float* __restrict__ be1,
    const float* __restrict__ We2, const float* __restrict__ be2,
    const int2* __restrict__ eix,
    float* __restrict__ hneigh, int N, int E, int T)
{
    __shared__ __attribute__((aligned(16))) float XCs[4][16 * 68];  // 17.4KB
    __shared__ __attribute__((aligned(16))) f16   Hbs[4][16 * 64];  // 8KB
    __shared__ int edsts[4][16];                                    // 256B

    const int tid  = threadIdx.x;
    const int w    = tid >> 6;
    const int lane = tid & 63;
    const int l15  = lane & 15;
    const int quad = lane >> 4;

    float* XC  = XCs[w];
    f16*   Hb  = Hbs[w];
    int*   edst = edsts[w];

    // Full weight sets in registers: wb1 (64 VGPR), wb2 (32 VGPR).
    f16x8 wb1[4][4];
#pragma unroll
    for (int kt = 0; kt < 4; ++kt)
#pragma unroll
        for (int nf = 0; nf < 4; ++nf) {
            int n = nf * 16 + l15;
#pragma unroll
            for (int j = 0; j < 8; ++j)
                wb1[kt][nf][j] = (f16)We1[(kt * 32 + quad * 8 + j) * 64 + n];
        }
    f16x8 wb2[2][4];
#pragma unroll
    for (int kt = 0; kt < 2; ++kt)
#pragma unroll
        for (int nf = 0; nf < 4; ++nf) {
            int n = nf * 16 + l15;
#pragma unroll
            for (int j = 0; j < 8; ++j)
                wb2[kt][nf][j] = (f16)We2[(kt * 32 + quad * 8 + j) * 64 + n];
        }

    float b1v[4], b2v[4];
#pragma unroll
    for (int nf = 0; nf < 4; ++nf) {
        b1v[nf] = be1[nf * 16 + l15];
        b2v[nf] = be2[nf * 16 + l15];
    }

    const int wid = blockIdx.x * 4 + w;   // global wave id
    const int nw  = gridDim.x * 4;

    // ---- pipeline prologue: tile0's x rows + tile1's edge indices ----
    int2 peC = eix[min(wid * 16 + l15, E - 1)];
    float4 s0, s1, s2, s3, d0v, d1v, d2v, d3v;
    {
        const float* ps = x + (size_t)peC.x * D;
        const float* pd = x + (size_t)peC.y * D;
        s0  = *(const float4*)(ps + quad * 8);
        s1  = *(const float4*)(ps + quad * 8 + 4);
        s2  = *(const float4*)(ps + 32 + quad * 8);
        s3  = *(const float4*)(ps + 32 + quad * 8 + 4);
        d0v = *(const float4*)(pd + quad * 8);
        d1v = *(const float4*)(pd + quad * 8 + 4);
        d2v = *(const float4*)(pd + 32 + quad * 8);
        d3v = *(const float4*)(pd + 32 + quad * 8 + 4);
    }
    int2 peN = eix[min((wid + nw) * 16 + l15, E - 1)];

    for (int tile = wid; tile < T; tile += nw) {
        const int e0 = tile * 16;

        int prevD = (e0 > 0)      ? eix[e0 - 1].y  : -2;   // wave-uniform
        int nextD = (e0 + 16 < E) ? eix[e0 + 16].y : -2;   // wave-uniform

        // ---- stage current tile (all from registers) ----
        *(float4*)&XC[l15 * 68 + quad * 8]          = s0;
        *(float4*)&XC[l15 * 68 + quad * 8 + 4]      = s1;
        *(float4*)&XC[l15 * 68 + 32 + quad * 8]     = s2;
        *(float4*)&XC[l15 * 68 + 32 + quad * 8 + 4] = s3;
        if (quad == 0) edst[l15] = (e0 + l15 < E) ? peC.y : N;

        f16x8 ah[4];
        ah[0][0]=(f16)s0.x; ah[0][1]=(f16)s0.y; ah[0][2]=(f16)s0.z; ah[0][3]=(f16)s0.w;
        ah[0][4]=(f16)s1.x; ah[0][5]=(f16)s1.y; ah[0][6]=(f16)s1.z; ah[0][7]=(f16)s1.w;
        ah[1][0]=(f16)s2.x; ah[1][1]=(f16)s2.y; ah[1][2]=(f16)s2.z; ah[1][3]=(f16)s2.w;
        ah[1][4]=(f16)s3.x; ah[1][5]=(f16)s3.y; ah[1][6]=(f16)s3.z; ah[1][7]=(f16)s3.w;
        ah[2][0]=(f16)d0v.x; ah[2][1]=(f16)d0v.y; ah[2][2]=(f16)d0v.z; ah[2][3]=(f16)d0v.w;
        ah[2][4]=(f16)d1v.x; ah[2][5]=(f16)d1v.y; ah[2][6]=(f16)d1v.z; ah[2][7]=(f16)d1v.w;
        ah[3][0]=(f16)d2v.x; ah[3][1]=(f16)d2v.y; ah[3][2]=(f16)d2v.z; ah[3][3]=(f16)d2v.w;
        ah[3][4]=(f16)d3v.x; ah[3][5]=(f16)d3v.y; ah[3][6]=(f16)d3v.z; ah[3][7]=(f16)d3v.w;

        // ---- prefetch: x rows for tile+nw, eix for tile+2nw ----
        float4 t0, t1, t2, t3, u0, u1, u2, u3;
        int2 peN2;
        {
            const float* ps2 = x + (size_t)peN.x * D;
            const float* pd2 = x + (size_t)peN.y * D;
            t0 = *(const float4*)(ps2 + quad * 8);
            t1 = *(const float4*)(ps2 + quad * 8 + 4);
            t2 = *(const float4*)(ps2 + 32 + quad * 8);
            t3 = *(const float4*)(ps2 + 32 + quad * 8 + 4);
            u0 = *(const float4*)(pd2 + quad * 8);
            u1 = *(const float4*)(pd2 + quad * 8 + 4);
            u2 = *(const float4*)(pd2 + 32 + quad * 8);
            u3 = *(const float4*)(pd2 + 32 + quad * 8 + 4);
            peN2 = eix[min((tile + 2 * nw) * 16 + l15, E - 1)];
        }

        // ---- GEMM1: [16,128]@[128,64] = 16 MFMA ----
        f32x4 acc[4] = {{0.f,0.f,0.f,0.f},{0.f,0.f,0.f,0.f},
                        {0.f,0.f,0.f,0.f},{0.f,0.f,0.f,0.f}};
#pragma unroll
        for (int kt = 0; kt < 4; ++kt)
#pragma unroll
            for (int nf = 0; nf < 4; ++nf)
                acc[nf] = __builtin_amdgcn_mfma_f32_16x16x32_f16(
                    ah[kt], wb1[kt][nf], acc[nf], 0, 0, 0);

        // ---- H = relu(acc+b1) -> Hbuf (ownership transpose) ----
#pragma unroll
        for (int nf = 0; nf < 4; ++nf)
#pragma unroll
            for (int i2 = 0; i2 < 4; ++i2)
                Hb[sw6(quad * 4 + i2, nf * 16 + l15)] =
                    (f16)fmaxf(acc[nf][i2] + b1v[nf], 0.f);

        // ---- GEMM2: [16,64]@[64,64] = 8 MFMA, A from Hbuf ----
        f32x4 dd[4] = {{0.f,0.f,0.f,0.f},{0.f,0.f,0.f,0.f},
                       {0.f,0.f,0.f,0.f},{0.f,0.f,0.f,0.f}};
#pragma unroll
        for (int kt = 0; kt < 2; ++kt) {
            f16x8 ah2 = *(const f16x8*)&Hb[sw6(l15, kt * 32 + quad * 8)];
#pragma unroll
            for (int nf = 0; nf < 4; ++nf)
                dd[nf] = __builtin_amdgcn_mfma_f32_16x16x32_f16(
                    ah2, wb2[kt][nf], dd[nf], 0, 0, 0);
        }

        // ---- contrib = xs * (d + b2), in-place in XC ----
#pragma unroll
        for (int nf = 0; nf < 4; ++nf)
#pragma unroll
            for (int i2 = 0; i2 < 4; ++i2) {
                int a = (quad * 4 + i2) * 68 + nf * 16 + l15;
                XC[a] = (dd[nf][i2] + b2v[nf]) * XC[a];
            }

        // ---- segmented sum over sorted dst runs (all 64 lanes = feature) ----
        {
            int j = lane;
            float a = 0.f;
            int cur = edst[0];
            int runStart = 0;
#pragma unroll
            for (int ii = 0; ii < 16; ++ii) {
                a += XC[ii * 68 + j];
                int nxt = (ii < 15) ? edst[ii + 1] : -3;
                if (nxt != cur) {
                    bool firstRun = (runStart == 0);
                    bool lastRun = (ii == 15) || (nxt >= N);
                    bool complete = (!firstRun || prevD != cur) &&
                                    (!lastRun || nextD != cur);
                    if (complete) hneigh[(size_t)cur * D + j] = a;
                    else atomicAdd(&hneigh[(size_t)cur * D + j], a);
                    a = 0.f; cur = nxt; runStart = ii + 1;
                }
            }
        }

        // ---- rotate pipeline registers ----
        s0 = t0; s1 = t1; s2 = t2; s3 = t3;
        d0v = u0; d1v = u1; d2v = u2; d3v = u3;
        peC = peN; peN = peN2;
        // NO barrier — stores retire asynchronously; next tile proceeds.
    }
}

// ---------------------------------------------------------------------------
// Node MLP via MFMA, weights in VGPR fragments, 2-term split.
// Grid = Tn exactly (one tile per block).
// ---------------------------------------------------------------------------
__global__ __launch_bounds__(256, 4) void node_mfma_kernel(
    float* __restrict__ h,
    const float* __restrict__ Wn, const float* __restrict__ bn,
    const float* __restrict__ Wg, const float* __restrict__ bg,
    float* __restrict__ gate, int N, int T)
{
    __shared__ __attribute__((aligned(16))) f16 ANhi[64 * 64];
    __shared__ __attribute__((aligned(16))) f16 ANlo[64 * 64];

    const int tid = threadIdx.x;
    const int w = tid >> 6;
    const int lane = tid & 63;
    const int l15 = lane & 15;
    const int quad = lane >> 4;
    const int m0 = w * 16;

    f16x8 wn[2][4];
#pragma unroll
    for (int kt = 0; kt < 2; ++kt)
#pragma unroll
        for (int nf = 0; nf < 4; ++nf) {
            int n = nf * 16 + l15;
#pragma unroll
            for (int j = 0; j < 8; ++j)
                wn[kt][nf][j] = (f16)Wn[(kt * 32 + quad * 8 + j) * 64 + n];
        }

    float bnv[4], wgv[4];
#pragma unroll
    for (int nt = 0; nt < 4; ++nt) {
        bnv[nt] = bn[nt * 16 + l15];
        wgv[nt] = Wg[nt * 16 + l15];
    }
    const float bgv = bg[0];

    for (int tile = blockIdx.x; tile < T; tile += gridDim.x) {
        const int t0 = tile * 64;

        {
            int i = tid >> 2;
            int q = tid & 3;
            int node = min(t0 + i, N - 1);
            const float* p = h + (size_t)node * D + q * 16;
#pragma unroll
            for (int r = 0; r < 4; ++r) {
                float4 v = *(const float4*)(p + r * 4);
                int k = q * 16 + r * 4;
                f16x4 hv, lv;
                hv[0] = (f16)v.x; lv[0] = (f16)(v.x - (float)hv[0]);
                hv[1] = (f16)v.y; lv[1] = (f16)(v.y - (float)hv[1]);
                hv[2] = (f16)v.z; lv[2] = (f16)(v.z - (float)hv[2]);
                hv[3] = (f16)v.w; lv[3] = (f16)(v.w - (float)hv[3]);
                *(f16x4*)&ANhi[sw6(i, k)] = hv;
                *(f16x4*)&ANlo[sw6(i, k)] = lv;
            }
        }
        __syncthreads();

        f32x4 cacc[4] = {{0.f,0.f,0.f,0.f},{0.f,0.f,0.f,0.f},{0.f,0.f,0.f,0.f},{0.f,0.f,0.f,0.f}};
#pragma unroll
        for (int kt = 0; kt < 2; ++kt) {
            int k = kt * 32 + quad * 8;
            f16x8 ah = *(const f16x8*)&ANhi[sw6(m0 + l15, k)];
            f16x8 al = *(const f16x8*)&ANlo[sw6(m0 + l15, k)];
#pragma unroll
            for (int nf = 0; nf < 4; ++nf) {
                cacc[nf] = __builtin_amdgcn_mfma_f32_16x16x32_f16(ah, wn[kt][nf], cacc[nf], 0, 0, 0);
                cacc[nf] = __builtin_amdgcn_mfma_f32_16x16x32_f16(al, wn[kt][nf], cacc[nf], 0, 0, 0);
            }
        }
        __syncthreads();

        float gpart[4] = {0.f, 0.f, 0.f, 0.f};
#pragma unroll
        for (int nt = 0; nt < 4; ++nt) {
            int n = nt * 16 + l15;
#pragma unroll
            for (int i2 = 0; i2 < 4; ++i2) {
                int m = t0 + m0 + quad * 4 + i2;
                float v = fmaxf(cacc[nt][i2] + bnv[nt], 0.f);
                if (m < N) h[(size_t)m * D + n] = v;
                gpart[i2] += v * wgv[nt];
            }
        }
#pragma unroll
        for (int s = 1; s < 16; s <<= 1) {
#pragma unroll
            for (int i2 = 0; i2 < 4; ++i2) gpart[i2] += __shfl_xor(gpart[i2], s);
        }
        if (l15 == 0) {
#pragma unroll
            for (int i2 = 0; i2 < 4; ++i2) {
                int m = t0 + m0 + quad * 4 + i2;
                if (m < N) gate[m] = gpart[i2] + bgv;
            }
        }
    }
}

// ---------------------------------------------------------------------------
// Pool SPLIT (r18/r19/r20 wins; PPARTS=16 => 2048 partial blocks, 8/CU).
// pool_partial computes LOCAL-max softmax partials (m_p, den_p, acc_p[64]);
// pool_combine rescales by exp(m_p - m) and applies the classifier.
// Exact up to fp reassociation. Partials overlay the dead eix2 region.
// ---------------------------------------------------------------------------
__global__ __launch_bounds__(256) void pool_partial(
    const float* __restrict__ h2,
    const float* __restrict__ gate,
    const int* __restrict__ gid,
    float* __restrict__ pm, float* __restrict__ pden,
    float* __restrict__ pacc, int N)
{
    int gb = blockIdx.x;
    int g = gb / PPARTS;
    int p = gb % PPARTS;
    int tid = threadIdx.x;

    int lo = 0, hi = N;
    while (lo < hi) { int mid = (lo + hi) >> 1; if (gid[mid] < g) lo = mid + 1; else hi = mid; }
    int s = lo;
    hi = N;
    while (lo < hi) { int mid = (lo + hi) >> 1; if (gid[mid] < g + 1) lo = mid + 1; else hi = mid; }
    int e = lo;

    int len = e - s;
    int st = s + (int)(((long long)len * p) / PPARTS);
    int en = s + (int)(((long long)len * (p + 1)) / PPARTS);

    __shared__ float red[256];
    __shared__ float accs[4][D];
    __shared__ float dens[4];

    // local max over this part
    float m = -INFINITY;
    for (int i = st + tid; i < en; i += 256) m = fmaxf(m, gate[i]);
    red[tid] = m;
    __syncthreads();
    for (int w = 128; w > 0; w >>= 1) {
        if (tid < w) red[tid] = fmaxf(red[tid], red[tid + w]);
        __syncthreads();
    }
    float lmax = red[0];
    __syncthreads();

    // weighted sums with local max
    int f = tid & (D - 1);
    int grp = tid >> 6;
    float acc = 0.0f, den = 0.0f;
    for (int i = st + grp; i < en; i += 4) {
        float wv = expf(gate[i] - lmax);
        acc += wv * h2[(size_t)i * D + f];
        if (f == 0) den += wv;
    }
    accs[grp][f] = acc;
    if (f == 0) dens[grp] = den;
    __syncthreads();

    if (tid < D)
        pacc[(size_t)gb * D + tid] =
            accs[0][tid] + accs[1][tid] + accs[2][tid] + accs[3][tid];
    if (tid == 0) {
        pden[gb] = dens[0] + dens[1] + dens[2] + dens[3];
        pm[gb] = lmax;
    }
}

__global__ __launch_bounds__(64) void pool_combine(
    const float* __restrict__ pm, const float* __restrict__ pden,
    const float* __restrict__ pacc,
    const float* __restrict__ Wfc, const float* __restrict__ bfc,
    float* __restrict__ out, int C)
{
    int g = blockIdx.x;
    int tid = threadIdx.x;   // 64 threads

    __shared__ float red[D];

    float m = -INFINITY;
#pragma unroll
    for (int p = 0; p < PPARTS; ++p) m = fmaxf(m, pm[g * PPARTS + p]);

    float den = 0.f, pf = 0.f;
#pragma unroll
    for (int p = 0; p < PPARTS; ++p) {
        float mp = pm[g * PPARTS + p];
        float sc = (mp > -INFINITY) ? expf(mp - m) : 0.f;
        den += pden[g * PPARTS + p] * sc;
        pf  += pacc[(size_t)(g * PPARTS + p) * D + tid] * sc;
    }
    red[tid] = (den > 0.f) ? (pf / den) : 0.f;
    __syncthreads();

    if (tid < C) {
        float o = bfc[tid];
#pragma unroll
        for (int k = 0; k < D; ++k) o += red[k] * Wfc[k * C + tid];
        out[g * C + tid] = o;
    }
}

extern "C" void kernel_launch(void* const* d_in, const int* in_sizes, int n_in,
                              void* d_out, int out_size, void* d_ws, size_t ws_size,
                              hipStream_t stream) {
    const float* x   = (const float*)d_in[0];
    const float* We1 = (const float*)d_in[1];
    const float* be1 = (const float*)d_in[2];
    const float* We2 = (const float*)d_in[3];
    const float* be2 = (const float*)d_in[4];
    const float* Wn  = (const float*)d_in[5];
    const float* bn  = (const float*)d_in[6];
    const float* Wg  = (const float*)d_in[7];
    const float* bg  = (const float*)d_in[8];
    const float* Wfc = (const float*)d_in[9];
    const float* bfc = (const float*)d_in[10];
    const int* src = (const int*)d_in[11];
    const int* dst = (const int*)d_in[12];
    const int* gid = (const int*)d_in[13];

    const int N = in_sizes[0] / D;
    const int E = in_sizes[11];
    const int C = 10;
    const int G = out_size / C;
    const int NB = (N + BNODES - 1) / BNODES;

    // workspace: eix2 | union{eixA, hneigh} | gate | bucket arrays
    // eix2 is dead after the edge kernel -> pool partials overlay it.
    int2*  eix2   = (int2*)d_ws;                          // [E]      12.8MB
    int2*  eixA   = eix2 + E;                             // [E]      12.8MB
    float* hneigh = (float*)eixA;                         // [(N+1)*64] 25.6MB (overlay)
    float* gate   = hneigh + (size_t)(N + 1) * D;         // [N]
    int*   bhist  = (int*)(gate + N);                     // [NB]
    int*   boff   = bhist + NB;                           // [NB+1]
    int*   bcursor= boff + NB + 1;                        // [NB]
    float* outp   = (float*)d_out;

    float* pm   = (float*)eix2;                           // [G*PPARTS] (overlay, post-edge)
    float* pden = pm + (size_t)G * PPARTS;                // [G*PPARTS]
    float* pacc = pden + (size_t)G * PPARTS;              // [G*PPARTS*D]

    const int Bh = (E + EB - 1) / EB;
    const int Te = (E + 15) / 16;     // 16-edge tiles, one wave each
    const int Tn = (N + 63) / 64;

    hipMemsetAsync(bhist, 0, (size_t)NB * sizeof(int), stream);

    bucket_hist<<<Bh, 256, 0, stream>>>(dst, bhist, E, NB);
    bucket_scan<<<1, 256, 0, stream>>>(bhist, boff, bcursor, NB);
    bucket_fill<<<Bh, 256, 0, stream>>>(dst, src, bcursor, eixA, E, NB);
    bucket_sort<<<NB, 256, 0, stream>>>(eixA, boff, eix2, NB);

    // eixA dead; zero hneigh (overlay) before edge kernel
    hipMemsetAsync(hneigh, 0, (size_t)(N + 1) * D * sizeof(float), stream);

    edge_mfma_kernel<<<512, 256, 0, stream>>>(x, We1, be1, We2, be2,
                                              eix2, hneigh, N, E, Te);
    node_mfma_kernel<<<Tn, 256, 0, stream>>>(hneigh, Wn, bn, Wg, bg, gate, N, Tn);
    pool_partial<<<G * PPARTS, 256, 0, stream>>>(hneigh, gate, gid,
                                                 pm, pden, pacc, N);
    pool_combine<<<G, 64, 0, stream>>>(pm, pden, pacc, Wfc, bfc, outp, C);
}

// Round 23
// 331.343 us; speedup vs baseline: 1.3872x; 1.0072x over previous
//
#include <hip/hip_runtime.h>
#include <hip/hip_bf16.h>

#define D 64
#define BSH 6            // log2(nodes per bucket)
#define BNODES 64
#define NBMAX 2048       // LDS hist capacity (N <= 131072)
#define EB 8192          // edges per hist/fill block
#define PPARTS 16        // pool partial blocks per graph

typedef _Float16 f16;
typedef _Float16 f16x4 __attribute__((ext_vector_type(4)));
typedef _Float16 f16x8 __attribute__((ext_vector_type(8)));
typedef float f32x4 __attribute__((ext_vector_type(4)));

__device__ __forceinline__ int sw6(int m, int k) {  // row stride 64 f16
    return (m << 6) + ((((k >> 3) ^ (m & 7)) & 7) << 3) + (k & 7);
}

// ---------------------------------------------------------------------------
// Bucket partition (coarse sort by dst>>6) — two-level LDS histograms.
// r23: hist PERSISTS its per-block lhist to blkhist (overlaid on the dead
// eix2 region: eix2 is first written by bucket_sort, after fill completes);
// fill loads it back instead of re-reading dst into LDS atomics.
// r21 LESSON (kept): hneigh overlays eixA — its memset must stay stream-
// ordered after bucket_sort (concurrent zeroing raced and crashed).
// ---------------------------------------------------------------------------
__global__ __launch_bounds__(256) void bucket_hist(
    const int* __restrict__ dst, int* __restrict__ bhist,
    int* __restrict__ blkhist, int E, int NB)
{
    __shared__ int lhist[NBMAX];
    int tid = threadIdx.x;
    for (int b = tid; b < NB; b += 256) lhist[b] = 0;
    __syncthreads();
    int base = blockIdx.x * EB;
#pragma unroll
    for (int r = 0; r < EB / 256; ++r) {
        int e = base + r * 256 + tid;
        if (e < E) atomicAdd(&lhist[dst[e] >> BSH], 1);
    }
    __syncthreads();
    int* myblk = blkhist + (size_t)blockIdx.x * NB;
    for (int b = tid; b < NB; b += 256) {
        int v = lhist[b];
        myblk[b] = v;                     // persist for bucket_fill
        if (v) atomicAdd(&bhist[b], v);
    }
}

__global__ __launch_bounds__(256) void bucket_scan(
    const int* __restrict__ bhist, int* __restrict__ boff,
    int* __restrict__ bcursor, int NB)
{
    __shared__ int lds[256];
    int tid = threadIdx.x;
    int chunk = (NB + 255) / 256;
    int b0 = tid * chunk;
    int b1 = min(b0 + chunk, NB);
    int s = 0;
    for (int b = b0; b < b1; ++b) s += bhist[b];
    lds[tid] = s;
    __syncthreads();
    for (int d2 = 1; d2 < 256; d2 <<= 1) {
        int v = (tid >= d2) ? lds[tid - d2] : 0;
        __syncthreads();
        lds[tid] += v;
        __syncthreads();
    }
    int run = (tid == 0) ? 0 : lds[tid - 1];
    for (int b = b0; b < b1; ++b) {
        boff[b] = run;
        bcursor[b] = run;
        run += bhist[b];
    }
    if (tid == 255) boff[NB] = lds[255];
}

// r23: no LDS histogram rebuild — lcur bases come from persisted blkhist.
__global__ __launch_bounds__(256) void bucket_fill(
    const int* __restrict__ dst, const int* __restrict__ src,
    const int* __restrict__ blkhist,
    int* __restrict__ bcursor, int2* __restrict__ eix, int E, int NB)
{
    __shared__ int lcur[NBMAX];
    int tid = threadIdx.x;
    int base = blockIdx.x * EB;

    // dv load: pure streaming, no dependent LDS atomics (latency-hidden)
    int dv[EB / 256];
#pragma unroll
    for (int r = 0; r < EB / 256; ++r) {
        int e = base + r * 256 + tid;
        dv[r] = (e < E) ? dst[e] : -1;
    }

    const int* myblk = blkhist + (size_t)blockIdx.x * NB;
    for (int b = tid; b < NB; b += 256) {
        int v = myblk[b];
        lcur[b] = v ? atomicAdd(&bcursor[b], v) : 0;
    }
    __syncthreads();
#pragma unroll
    for (int r = 0; r < EB / 256; ++r) {
        int e = base + r * 256 + tid;
        if (dv[r] >= 0) {
            int p = atomicAdd(&lcur[dv[r] >> BSH], 1);
            eix[p] = make_int2(src[e], dv[r]);
        }
    }
}

// ---------------------------------------------------------------------------
// Per-bucket exact counting sort (64 bins in LDS) -> globally dst-sorted eix2.
// ---------------------------------------------------------------------------
__global__ __launch_bounds__(256) void bucket_sort(
    const int2* __restrict__ eix, const int* __restrict__ boff,
    int2* __restrict__ eix2, int NB)
{
    __shared__ int h64[BNODES];
    __shared__ int cur64[BNODES];
    int bk = blockIdx.x;
    int s = boff[bk], e = boff[bk + 1];
    int tid = threadIdx.x;
    int nbase = bk << BSH;

    if (tid < BNODES) h64[tid] = 0;
    __syncthreads();
    for (int i = s + tid; i < e; i += 256)
        atomicAdd(&h64[eix[i].y - nbase], 1);
    __syncthreads();
    if (tid < BNODES) {
        int v = h64[tid];
        int inc = v;
        for (int d2 = 1; d2 < BNODES; d2 <<= 1) {   // wave-level inclusive scan
            int t = __shfl_up(inc, d2);
            if (tid >= d2) inc += t;
        }
        cur64[tid] = inc - v;                        // exclusive prefix
    }
    __syncthreads();
    for (int i = s + tid; i < e; i += 256) {
        int2 ed = eix[i];
        int slot = atomicAdd(&cur64[ed.y - nbase], 1);
        eix2[s + slot] = ed;
    }
}

// ---------------------------------------------------------------------------
// Edge MLP via MFMA — barrier-free wave-independent tiles + register pipeline
// (r10 structure, best measured: 143.9-147.2us, bank conflicts 0, VGPR 108).
//
// Ledger: r0 192 lockstep; r1/r9 forced-occ SPILL; r5 occ-lockstep dead;
// r6 prefetch-lockstep neutral; r8 barrier-free 154; r10 reg-pipeline 144.5;
// r14 2-way ILP neutral (LDS-instruction-stream bound); r17 coop REGRESSED;
// r18 pool-split WIN; r19 PPARTS8+node-grid WIN; r20 EB8192+PPARTS16 WIN
// (334.7, reproduced 333.7); r21 concurrent-zero REFUTED (aliasing).
// ---------------------------------------------------------------------------
__global__ __launch_bounds__(256, 2) void edge_mfma_kernel(
    const float* __restrict__ x,
    const float* __restrict__ We1, const float* __restrict__ be1,
    const float* __restrict__ We2, const float* __restrict__ be2,
    const int2* __restrict__ eix,
    float* __restrict__ hneigh, int N, int E, int T)
{
    __shared__ __attribute__((aligned(16))) float XCs[4][16 * 68];  // 17.4KB
    __shared__ __attribute__((aligned(16))) f16   Hbs[4][16 * 64];  // 8KB
    __shared__ int edsts[4][16];                                    // 256B

    const int tid  = threadIdx.x;
    const int w    = tid >> 6;
    const int lane = tid & 63;
    const int l15  = lane & 15;
    const int quad = lane >> 4;

    float* XC  = XCs[w];
    f16*   Hb  = Hbs[w];
    int*   edst = edsts[w];

    // Full weight sets in registers: wb1 (64 VGPR), wb2 (32 VGPR).
    f16x8 wb1[4][4];
#pragma unroll
    for (int kt = 0; kt < 4; ++kt)
#pragma unroll
        for (int nf = 0; nf < 4; ++nf) {
            int n = nf * 16 + l15;
#pragma unroll
            for (int j = 0; j < 8; ++j)
                wb1[kt][nf][j] = (f16)We1[(kt * 32 + quad * 8 + j) * 64 + n];
        }
    f16x8 wb2[2][4];
#pragma unroll
    for (int kt = 0; kt < 2; ++kt)
#pragma unroll
        for (int nf = 0; nf < 4; ++nf) {
            int n = nf * 16 + l15;
#pragma unroll
            for (int j = 0; j < 8; ++j)
                wb2[kt][nf][j] = (f16)We2[(kt * 32 + quad * 8 + j) * 64 + n];
        }

    float b1v[4], b2v[4];
#pragma unroll
    for (int nf = 0; nf < 4; ++nf) {
        b1v[nf] = be1[nf * 16 + l15];
        b2v[nf] = be2[nf * 16 + l15];
    }

    const int wid = blockIdx.x * 4 + w;   // global wave id
    const int nw  = gridDim.x * 4;

    // ---- pipeline prologue: tile0's x rows + tile1's edge indices ----
    int2 peC = eix[min(wid * 16 + l15, E - 1)];
    float4 s0, s1, s2, s3, d0v, d1v, d2v, d3v;
    {
        const float* ps = x + (size_t)peC.x * D;
        const float* pd = x + (size_t)peC.y * D;
        s0  = *(const float4*)(ps + quad * 8);
        s1  = *(const float4*)(ps + quad * 8 + 4);
        s2  = *(const float4*)(ps + 32 + quad * 8);
        s3  = *(const float4*)(ps + 32 + quad * 8 + 4);
        d0v = *(const float4*)(pd + quad * 8);
        d1v = *(const float4*)(pd + quad * 8 + 4);
        d2v = *(const float4*)(pd + 32 + quad * 8);
        d3v = *(const float4*)(pd + 32 + quad * 8 + 4);
    }
    int2 peN = eix[min((wid + nw) * 16 + l15, E - 1)];

    for (int tile = wid; tile < T; tile += nw) {
        const int e0 = tile * 16;

        int prevD = (e0 > 0)      ? eix[e0 - 1].y  : -2;   // wave-uniform
        int nextD = (e0 + 16 < E) ? eix[e0 + 16].y : -2;   // wave-uniform

        // ---- stage current tile (all from registers) ----
        *(float4*)&XC[l15 * 68 + quad * 8]          = s0;
        *(float4*)&XC[l15 * 68 + quad * 8 + 4]      = s1;
        *(float4*)&XC[l15 * 68 + 32 + quad * 8]     = s2;
        *(float4*)&XC[l15 * 68 + 32 + quad * 8 + 4] = s3;
        if (quad == 0) edst[l15] = (e0 + l15 < E) ? peC.y : N;

        f16x8 ah[4];
        ah[0][0]=(f16)s0.x; ah[0][1]=(f16)s0.y; ah[0][2]=(f16)s0.z; ah[0][3]=(f16)s0.w;
        ah[0][4]=(f16)s1.x; ah[0][5]=(f16)s1.y; ah[0][6]=(f16)s1.z; ah[0][7]=(f16)s1.w;
        ah[1][0]=(f16)s2.x; ah[1][1]=(f16)s2.y; ah[1][2]=(f16)s2.z; ah[1][3]=(f16)s2.w;
        ah[1][4]=(f16)s3.x; ah[1][5]=(f16)s3.y; ah[1][6]=(f16)s3.z; ah[1][7]=(f16)s3.w;
        ah[2][0]=(f16)d0v.x; ah[2][1]=(f16)d0v.y; ah[2][2]=(f16)d0v.z; ah[2][3]=(f16)d0v.w;
        ah[2][4]=(f16)d1v.x; ah[2][5]=(f16)d1v.y; ah[2][6]=(f16)d1v.z; ah[2][7]=(f16)d1v.w;
        ah[3][0]=(f16)d2v.x; ah[3][1]=(f16)d2v.y; ah[3][2]=(f16)d2v.z; ah[3][3]=(f16)d2v.w;
        ah[3][4]=(f16)d3v.x; ah[3][5]=(f16)d3v.y; ah[3][6]=(f16)d3v.z; ah[3][7]=(f16)d3v.w;

        // ---- prefetch: x rows for tile+nw, eix for tile+2nw ----
        float4 t0, t1, t2, t3, u0, u1, u2, u3;
        int2 peN2;
        {
            const float* ps2 = x + (size_t)peN.x * D;
            const float* pd2 = x + (size_t)peN.y * D;
            t0 = *(const float4*)(ps2 + quad * 8);
            t1 = *(const float4*)(ps2 + quad * 8 + 4);
            t2 = *(const float4*)(ps2 + 32 + quad * 8);
            t3 = *(const float4*)(ps2 + 32 + quad * 8 + 4);
            u0 = *(const float4*)(pd2 + quad * 8);
            u1 = *(const float4*)(pd2 + quad * 8 + 4);
            u2 = *(const float4*)(pd2 + 32 + quad * 8);
            u3 = *(const float4*)(pd2 + 32 + quad * 8 + 4);
            peN2 = eix[min((tile + 2 * nw) * 16 + l15, E - 1)];
        }

        // ---- GEMM1: [16,128]@[128,64] = 16 MFMA ----
        f32x4 acc[4] = {{0.f,0.f,0.f,0.f},{0.f,0.f,0.f,0.f},
                        {0.f,0.f,0.f,0.f},{0.f,0.f,0.f,0.f}};
#pragma unroll
        for (int kt = 0; kt < 4; ++kt)
#pragma unroll
            for (int nf = 0; nf < 4; ++nf)
                acc[nf] = __builtin_amdgcn_mfma_f32_16x16x32_f16(
                    ah[kt], wb1[kt][nf], acc[nf], 0, 0, 0);

        // ---- H = relu(acc+b1) -> Hbuf (ownership transpose) ----
#pragma unroll
        for (int nf = 0; nf < 4; ++nf)
#pragma unroll
            for (int i2 = 0; i2 < 4; ++i2)
                Hb[sw6(quad * 4 + i2, nf * 16 + l15)] =
                    (f16)fmaxf(acc[nf][i2] + b1v[nf], 0.f);

        // ---- GEMM2: [16,64]@[64,64] = 8 MFMA, A from Hbuf ----
        f32x4 dd[4] = {{0.f,0.f,0.f,0.f},{0.f,0.f,0.f,0.f},
                       {0.f,0.f,0.f,0.f},{0.f,0.f,0.f,0.f}};
#pragma unroll
        for (int kt = 0; kt < 2; ++kt) {
            f16x8 ah2 = *(const f16x8*)&Hb[sw6(l15, kt * 32 + quad * 8)];
#pragma unroll
            for (int nf = 0; nf < 4; ++nf)
                dd[nf] = __builtin_amdgcn_mfma_f32_16x16x32_f16(
                    ah2, wb2[kt][nf], dd[nf], 0, 0, 0);
        }

        // ---- contrib = xs * (d + b2), in-place in XC ----
#pragma unroll
        for (int nf = 0; nf < 4; ++nf)
#pragma unroll
            for (int i2 = 0; i2 < 4; ++i2) {
                int a = (quad * 4 + i2) * 68 + nf * 16 + l15;
                XC[a] = (dd[nf][i2] + b2v[nf]) * XC[a];
            }

        // ---- segmented sum over sorted dst runs (all 64 lanes = feature) ----
        {
            int j = lane;
            float a = 0.f;
            int cur = edst[0];
            int runStart = 0;
#pragma unroll
            for (int ii = 0; ii < 16; ++ii) {
                a += XC[ii * 68 + j];
                int nxt = (ii < 15) ? edst[ii + 1] : -3;
                if (nxt != cur) {
                    bool firstRun = (runStart == 0);
                    bool lastRun = (ii == 15) || (nxt >= N);
                    bool complete = (!firstRun || prevD != cur) &&
                                    (!lastRun || nextD != cur);
                    if (complete) hneigh[(size_t)cur * D + j] = a;
                    else atomicAdd(&hneigh[(size_t)cur * D + j], a);
                    a = 0.f; cur = nxt; runStart = ii + 1;
                }
            }
        }

        // ---- rotate pipeline registers ----
        s0 = t0; s1 = t1; s2 = t2; s3 = t3;
        d0v = u0; d1v = u1; d2v = u2; d3v = u3;
        peC = peN; peN = peN2;
        // NO barrier — stores retire asynchronously; next tile proceeds.
    }
}

// ---------------------------------------------------------------------------
// Node MLP via MFMA, weights in VGPR fragments, 2-term split.
// Grid = Tn exactly (one tile per block).
// ---------------------------------------------------------------------------
__global__ __launch_bounds__(256, 4) void node_mfma_kernel(
    float* __restrict__ h,
    const float* __restrict__ Wn, const float* __restrict__ bn,
    const float* __restrict__ Wg, const float* __restrict__ bg,
    float* __restrict__ gate, int N, int T)
{
    __shared__ __attribute__((aligned(16))) f16 ANhi[64 * 64];
    __shared__ __attribute__((aligned(16))) f16 ANlo[64 * 64];

    const int tid = threadIdx.x;
    const int w = tid >> 6;
    const int lane = tid & 63;
    const int l15 = lane & 15;
    const int quad = lane >> 4;
    const int m0 = w * 16;

    f16x8 wn[2][4];
#pragma unroll
    for (int kt = 0; kt < 2; ++kt)
#pragma unroll
        for (int nf = 0; nf < 4; ++nf) {
            int n = nf * 16 + l15;
#pragma unroll
            for (int j = 0; j < 8; ++j)
                wn[kt][nf][j] = (f16)Wn[(kt * 32 + quad * 8 + j) * 64 + n];
        }

    float bnv[4], wgv[4];
#pragma unroll
    for (int nt = 0; nt < 4; ++nt) {
        bnv[nt] = bn[nt * 16 + l15];
        wgv[nt] = Wg[nt * 16 + l15];
    }
    const float bgv = bg[0];

    for (int tile = blockIdx.x; tile < T; tile += gridDim.x) {
        const int t0 = tile * 64;

        {
            int i = tid >> 2;
            int q = tid & 3;
            int node = min(t0 + i, N - 1);
            const float* p = h + (size_t)node * D + q * 16;
#pragma unroll
            for (int r = 0; r < 4; ++r) {
                float4 v = *(const float4*)(p + r * 4);
                int k = q * 16 + r * 4;
                f16x4 hv, lv;
                hv[0] = (f16)v.x; lv[0] = (f16)(v.x - (float)hv[0]);
                hv[1] = (f16)v.y; lv[1] = (f16)(v.y - (float)hv[1]);
                hv[2] = (f16)v.z; lv[2] = (f16)(v.z - (float)hv[2]);
                hv[3] = (f16)v.w; lv[3] = (f16)(v.w - (float)hv[3]);
                *(f16x4*)&ANhi[sw6(i, k)] = hv;
                *(f16x4*)&ANlo[sw6(i, k)] = lv;
            }
        }
        __syncthreads();

        f32x4 cacc[4] = {{0.f,0.f,0.f,0.f},{0.f,0.f,0.f,0.f},{0.f,0.f,0.f,0.f},{0.f,0.f,0.f,0.f}};
#pragma unroll
        for (int kt = 0; kt < 2; ++kt) {
            int k = kt * 32 + quad * 8;
            f16x8 ah = *(const f16x8*)&ANhi[sw6(m0 + l15, k)];
            f16x8 al = *(const f16x8*)&ANlo[sw6(m0 + l15, k)];
#pragma unroll
            for (int nf = 0; nf < 4; ++nf) {
                cacc[nf] = __builtin_amdgcn_mfma_f32_16x16x32_f16(ah, wn[kt][nf], cacc[nf], 0, 0, 0);
                cacc[nf] = __builtin_amdgcn_mfma_f32_16x16x32_f16(al, wn[kt][nf], cacc[nf], 0, 0, 0);
            }
        }
        __syncthreads();

        float gpart[4] = {0.f, 0.f, 0.f, 0.f};
#pragma unroll
        for (int nt = 0; nt < 4; ++nt) {
            int n = nt * 16 + l15;
#pragma unroll
            for (int i2 = 0; i2 < 4; ++i2) {
                int m = t0 + m0 + quad * 4 + i2;
                float v = fmaxf(cacc[nt][i2] + bnv[nt], 0.f);
                if (m < N) h[(size_t)m * D + n] = v;
                gpart[i2] += v * wgv[nt];
            }
        }
#pragma unroll
        for (int s = 1; s < 16; s <<= 1) {
#pragma unroll
            for (int i2 = 0; i2 < 4; ++i2) gpart[i2] += __shfl_xor(gpart[i2], s);
        }
        if (l15 == 0) {
#pragma unroll
            for (int i2 = 0; i2 < 4; ++i2) {
                int m = t0 + m0 + quad * 4 + i2;
                if (m < N) gate[m] = gpart[i2] + bgv;
            }
        }
    }
}

// ---------------------------------------------------------------------------
// Pool SPLIT (r18/r19/r20 wins; PPARTS=16 => 2048 partial blocks, 8/CU).
// pool_partial computes LOCAL-max softmax partials (m_p, den_p, acc_p[64]);
// pool_combine rescales by exp(m_p - m) and applies the classifier.
// Exact up to fp reassociation. Partials overlay the dead eix2 region.
// ---------------------------------------------------------------------------
__global__ __launch_bounds__(256) void pool_partial(
    const float* __restrict__ h2,
    const float* __restrict__ gate,
    const int* __restrict__ gid,
    float* __restrict__ pm, float* __restrict__ pden,
    float* __restrict__ pacc, int N)
{
    int gb = blockIdx.x;
    int g = gb / PPARTS;
    int p = gb % PPARTS;
    int tid = threadIdx.x;

    int lo = 0, hi = N;
    while (lo < hi) { int mid = (lo + hi) >> 1; if (gid[mid] < g) lo = mid + 1; else hi = mid; }
    int s = lo;
    hi = N;
    while (lo < hi) { int mid = (lo + hi) >> 1; if (gid[mid] < g + 1) lo = mid + 1; else hi = mid; }
    int e = lo;

    int len = e - s;
    int st = s + (int)(((long long)len * p) / PPARTS);
    int en = s + (int)(((long long)len * (p + 1)) / PPARTS);

    __shared__ float red[256];
    __shared__ float accs[4][D];
    __shared__ float dens[4];

    // local max over this part
    float m = -INFINITY;
    for (int i = st + tid; i < en; i += 256) m = fmaxf(m, gate[i]);
    red[tid] = m;
    __syncthreads();
    for (int w = 128; w > 0; w >>= 1) {
        if (tid < w) red[tid] = fmaxf(red[tid], red[tid + w]);
        __syncthreads();
    }
    float lmax = red[0];
    __syncthreads();

    // weighted sums with local max
    int f = tid & (D - 1);
    int grp = tid >> 6;
    float acc = 0.0f, den = 0.0f;
    for (int i = st + grp; i < en; i += 4) {
        float wv = expf(gate[i] - lmax);
        acc += wv * h2[(size_t)i * D + f];
        if (f == 0) den += wv;
    }
    accs[grp][f] = acc;
    if (f == 0) dens[grp] = den;
    __syncthreads();

    if (tid < D)
        pacc[(size_t)gb * D + tid] =
            accs[0][tid] + accs[1][tid] + accs[2][tid] + accs[3][tid];
    if (tid == 0) {
        pden[gb] = dens[0] + dens[1] + dens[2] + dens[3];
        pm[gb] = lmax;
    }
}

__global__ __launch_bounds__(64) void pool_combine(
    const float* __restrict__ pm, const float* __restrict__ pden,
    const float* __restrict__ pacc,
    const float* __restrict__ Wfc, const float* __restrict__ bfc,
    float* __restrict__ out, int C)
{
    int g = blockIdx.x;
    int tid = threadIdx.x;   // 64 threads

    __shared__ float red[D];

    float m = -INFINITY;
#pragma unroll
    for (int p = 0; p < PPARTS; ++p) m = fmaxf(m, pm[g * PPARTS + p]);

    float den = 0.f, pf = 0.f;
#pragma unroll
    for (int p = 0; p < PPARTS; ++p) {
        float mp = pm[g * PPARTS + p];
        float sc = (mp > -INFINITY) ? expf(mp - m) : 0.f;
        den += pden[g * PPARTS + p] * sc;
        pf  += pacc[(size_t)(g * PPARTS + p) * D + tid] * sc;
    }
    red[tid] = (den > 0.f) ? (pf / den) : 0.f;
    __syncthreads();

    if (tid < C) {
        float o = bfc[tid];
#pragma unroll
        for (int k = 0; k < D; ++k) o += red[k] * Wfc[k * C + tid];
        out[g * C + tid] = o;
    }
}

extern "C" void kernel_launch(void* const* d_in, const int* in_sizes, int n_in,
                              void* d_out, int out_size, void* d_ws, size_t ws_size,
                              hipStream_t stream) {
    const float* x   = (const float*)d_in[0];
    const float* We1 = (const float*)d_in[1];
    const float* be1 = (const float*)d_in[2];
    const float* We2 = (const float*)d_in[3];
    const float* be2 = (const float*)d_in[4];
    const float* Wn  = (const float*)d_in[5];
    const float* bn  = (const float*)d_in[6];
    const float* Wg  = (const float*)d_in[7];
    const float* bg  = (const float*)d_in[8];
    const float* Wfc = (const float*)d_in[9];
    const float* bfc = (const float*)d_in[10];
    const int* src = (const int*)d_in[11];
    const int* dst = (const int*)d_in[12];
    const int* gid = (const int*)d_in[13];

    const int N = in_sizes[0] / D;
    const int E = in_sizes[11];
    const int C = 10;
    const int G = out_size / C;
    const int NB = (N + BNODES - 1) / BNODES;

    // workspace: eix2 | union{eixA, hneigh} | gate | bucket arrays
    // eix2's region is multiply-overlaid across disjoint lifetimes:
    //   [hist..fill]  blkhist (per-block histograms, r23)
    //   [sort..edge]  eix2 (sorted edge list)
    //   [pool]        pm/pden/pacc (softmax partials)
    int2*  eix2   = (int2*)d_ws;                          // [E]      12.8MB
    int2*  eixA   = eix2 + E;                             // [E]      12.8MB
    float* hneigh = (float*)eixA;                         // [(N+1)*64] 25.6MB (overlay)
    float* gate   = hneigh + (size_t)(N + 1) * D;         // [N]
    int*   bhist  = (int*)(gate + N);                     // [NB]
    int*   boff   = bhist + NB;                           // [NB+1]
    int*   bcursor= boff + NB + 1;                        // [NB]
    float* outp   = (float*)d_out;

    int*   blkhist = (int*)eix2;                          // [Bh*NB] (overlay, pre-sort)
    float* pm   = (float*)eix2;                           // [G*PPARTS] (overlay, post-edge)
    float* pden = pm + (size_t)G * PPARTS;                // [G*PPARTS]
    float* pacc = pden + (size_t)G * PPARTS;              // [G*PPARTS*D]

    const int Bh = (E + EB - 1) / EB;
    const int Te = (E + 15) / 16;     // 16-edge tiles, one wave each
    const int Tn = (N + 63) / 64;

    hipMemsetAsync(bhist, 0, (size_t)NB * sizeof(int), stream);

    bucket_hist<<<Bh, 256, 0, stream>>>(dst, bhist, blkhist, E, NB);
    bucket_scan<<<1, 256, 0, stream>>>(bhist, boff, bcursor, NB);
    bucket_fill<<<Bh, 256, 0, stream>>>(dst, src, blkhist, bcursor, eixA, E, NB);
    bucket_sort<<<NB, 256, 0, stream>>>(eixA, boff, eix2, NB);

    // eixA dead; zero hneigh (overlay) before edge kernel
    hipMemsetAsync(hneigh, 0, (size_t)(N + 1) * D * sizeof(float), stream);

    edge_mfma_kernel<<<512, 256, 0, stream>>>(x, We1, be1, We2, be2,
                                              eix2, hneigh, N, E, Te);
    node_mfma_kernel<<<Tn, 256, 0, stream>>>(hneigh, Wn, bn, Wg, bg, gate, N, Tn);
    pool_partial<<<G * PPARTS, 256, 0, stream>>>(hneigh, gate, gid,
                                                 pm, pden, pacc, N);
    pool_combine<<<G, 64, 0, stream>>>(pm, pden, pacc, Wfc, bfc, outp, C);
}